// Round 7
// baseline (2921.439 us; speedup 1.0000x reference)
//
#include <hip/hip_runtime.h>

#define GLOBAL_AS __attribute__((address_space(1)))
#define LDS_AS __attribute__((address_space(3)))

typedef unsigned short u16;
typedef unsigned int u32;
typedef __attribute__((ext_vector_type(4))) float f32x4;
typedef __attribute__((ext_vector_type(8))) short bf16x8;

// Model dims
#define TT 2048
#define EE 1024
#define NHH 16
#define HDD 64
#define HIDD 2816
#define VV 32000
#define MM 4096   // B*T

__device__ __forceinline__ u16 f2bf(float f) {
  u32 u = __builtin_bit_cast(u32, f);
  u += 0x7fffu + ((u >> 16) & 1u);
  return (u16)(u >> 16);
}
__device__ __forceinline__ float bf2f(u16 v) {
  return __builtin_bit_cast(float, (u32)v << 16);
}

// ---------------- elementwise / staging kernels ----------------

__global__ __launch_bounds__(256) void castbf_k(const float* __restrict__ in,
                                                u16* __restrict__ o, long n4) {
  const long i = (long)blockIdx.x * 256 + threadIdx.x;
  if (i >= n4) return;
  const float4 v = ((const float4*)in)[i];
  ((uint2*)o)[i] = make_uint2((u32)f2bf(v.x) | ((u32)f2bf(v.y) << 16),
                              (u32)f2bf(v.z) | ((u32)f2bf(v.w) << 16));
}

__global__ void ropetab_k(float* __restrict__ cosT, float* __restrict__ sinT) {
  const int t = blockIdx.x, j = threadIdx.x;  // j in [0,32)
  const float inv = powf(10000.0f, -(float)j * (1.0f / 32.0f));
  const float f = (float)t * inv;
  cosT[t * 32 + j] = cosf(f);
  sinT[t * 32 + j] = sinf(f);
}

__global__ __launch_bounds__(256) void embed_k(const int* __restrict__ idx,
                                               const float* __restrict__ temb,
                                               float* __restrict__ x) {
  const int row = blockIdx.x;
  const int id = idx[row];
  ((float4*)(x + (size_t)row * EE))[threadIdx.x] =
      ((const float4*)(temb + (size_t)id * EE))[threadIdx.x];
}

__global__ __launch_bounds__(256) void rmsnorm_k(const float* __restrict__ x,
                                                 const float* __restrict__ w,
                                                 u16* __restrict__ o) {
  __shared__ float red[4];
  const int row = blockIdx.x, tid = threadIdx.x;
  const float4 v = ((const float4*)(x + (size_t)row * EE))[tid];
  float ss = v.x * v.x + v.y * v.y + v.z * v.z + v.w * v.w;
#pragma unroll
  for (int off = 32; off; off >>= 1) ss += __shfl_xor(ss, off, 64);
  if ((tid & 63) == 0) red[tid >> 6] = ss;
  __syncthreads();
  const float inv = rsqrtf((red[0] + red[1] + red[2] + red[3]) * (1.0f / 1024.0f) + 1e-6f);
  const float4 wv = ((const float4*)w)[tid];
  const u32 lo = (u32)f2bf(v.x * inv * wv.x) | ((u32)f2bf(v.y * inv * wv.y) << 16);
  const u32 hi = (u32)f2bf(v.z * inv * wv.z) | ((u32)f2bf(v.w * inv * wv.w) << 16);
  ((uint2*)(o + (size_t)row * EE))[tid] = make_uint2(lo, hi);
}

// ---------------- GEMM engine: 256x256, BK=32, 3-buffer ring, reads-before-barrier ----------------
// C[M,N] = A[M,K] * B[N,K]^T, bf16 in, f32 accum. M = 4096.
// m201-faithful phase: {ds_read frags; issue glds for kt+2; counted vmcnt; ONE barrier;
// setprio(1) MFMA setprio(0)}. Reads ride the previous phase's vmcnt+barrier guarantee;
// read latency drains under the barrier; next phase's reads overlap this MFMA's execution.
// 2 phases per K-tile (p0: m0-3 x n0-3 + A-glds ; p1: m4-7 x n0-3 + B-glds + vmcnt(4)).
// vmcnt(4): outstanding = kt+1 (<=4, must land) + kt+2 (4, in flight) -> never drains.
// OUTBF: 0 f32 C ; 1 bf16 C16 ; 2 C16 = silu(G)*acc ; 3 rope-split -> Qb/Kb/Vtb (Q pre-scaled 1/8).
// SWZ: XCD-grouped mapping (16 row-blocks of one col-tile pinned per XCD), pad+early-exit.
template <int OUTBF, int SWZ>
__global__ __launch_bounds__(512, 2) void gemm256p(const u16* __restrict__ A,
                                                   const u16* __restrict__ Bw,
                                                   float* __restrict__ C,
                                                   u16* __restrict__ C16,
                                                   const u16* __restrict__ G,
                                                   const float* __restrict__ cosT,
                                                   const float* __restrict__ sinT,
                                                   u16* __restrict__ Qb,
                                                   u16* __restrict__ Kb,
                                                   u16* __restrict__ Vtb,
                                                   int N, int K) {
  __shared__ u16 lds[3 * 16384];  // 96 KB: 3 ring buffers x (A 256x32 | B 256x32)
  const int t = threadIdx.x;
  const int lane = t & 63;
  const int wid = t >> 6;
  const int wr = wid >> 2;   // 0..1
  const int wc = wid & 3;    // 0..3
  const int l15 = lane & 15, lg = lane >> 4;
  const int bid = blockIdx.x;
  int row0, col0;
  if (SWZ) {
    const int c = (bid & 7) + 8 * (bid >> 7);   // col-tile, pinned to XCD = bid&7
    const int r = (bid >> 3) & 15;              // row-tile
    if (c * 256 >= N) return;
    row0 = r << 8;
    col0 = c << 8;
  } else {
    row0 = (bid & 15) << 8;
    col0 = (bid >> 4) << 8;
  }
  const int NT = K >> 5;

  // staging: thread t -> row t>>2 (0..127), 16B unit t&3, pre-swizzled source
  const int rA = t >> 2;
  const int usw = (((t & 3) ^ ((t >> 3) & 3)) << 3);
  const u16* sA0 = A + (size_t)(row0 + rA) * K + usw;
  const u16* sA1 = A + (size_t)(row0 + 128 + rA) * K + usw;
  const u16* sB0 = Bw + (size_t)(col0 + rA) * K + usw;
  const u16* sB1 = Bw + (size_t)(col0 + 128 + rA) * K + usw;
  const int dst = t << 3;

  // fragment read offsets (swizzle matches staging: 2-way = free)
  const int e8 = ((lg ^ ((l15 >> 1) & 3)) << 3);
  const int aoff = (wr * 128 + l15) * 32 + e8;
  const int boff = 8192 + (wc * 64 + l15) * 32 + e8;

  f32x4 acc[8][4] = {};

  auto stageA = [&](int kt, int buf) {
    u16* b = &lds[buf * 16384];
    const size_t ko = (size_t)kt * 32;
    __builtin_amdgcn_global_load_lds((const GLOBAL_AS void*)(sA0 + ko),
                                     (LDS_AS void*)(b + dst), 16, 0, 0);
    __builtin_amdgcn_global_load_lds((const GLOBAL_AS void*)(sA1 + ko),
                                     (LDS_AS void*)(b + 4096 + dst), 16, 0, 0);
  };
  auto stageB = [&](int kt, int buf) {
    u16* b = &lds[buf * 16384];
    const size_t ko = (size_t)kt * 32;
    __builtin_amdgcn_global_load_lds((const GLOBAL_AS void*)(sB0 + ko),
                                     (LDS_AS void*)(b + 8192 + dst), 16, 0, 0);
    __builtin_amdgcn_global_load_lds((const GLOBAL_AS void*)(sB1 + ko),
                                     (LDS_AS void*)(b + 12288 + dst), 16, 0, 0);
  };

  // prologue: stage tiles 0 and 1; vmcnt(4) -> tile 0 landed, tile 1 in flight
  stageA(0, 0); stageB(0, 0);
  stageA(1, 1); stageB(1, 1);
  asm volatile("s_waitcnt vmcnt(4)" ::: "memory");
  __builtin_amdgcn_s_barrier();

  int cbuf = 0;
  for (int kt = 0; kt < NT; ++kt) {
    const u16* cb = &lds[cbuf * 16384];
    const int nbuf = (cbuf == 2) ? 0 : cbuf + 1;   // buffer of kt+2 == buffer of kt-1 (freed)
    const int sbuf = (nbuf == 2) ? 0 : nbuf + 1;
    const bool st = (kt + 2 < NT);
    bf16x8 af[8], bfv[4];

    // ---- phase 0: reads (covered by previous vmcnt+barrier), A-glds, barrier, MFMA m0-3 ----
#pragma unroll
    for (int m = 0; m < 4; ++m) af[m] = *(const bf16x8*)&cb[aoff + m * 512];
#pragma unroll
    for (int n = 0; n < 4; ++n) bfv[n] = *(const bf16x8*)&cb[boff + n * 512];
    if (st) stageA(kt + 2, sbuf);
    __builtin_amdgcn_s_barrier();
    __builtin_amdgcn_s_setprio(1);
#pragma unroll
    for (int m = 0; m < 4; ++m)
#pragma unroll
      for (int n = 0; n < 4; ++n)
        acc[m][n] = __builtin_amdgcn_mfma_f32_16x16x32_bf16(af[m], bfv[n], acc[m][n], 0, 0, 0);
    __builtin_amdgcn_s_setprio(0);

    // ---- phase 1: reads A4-7, B-glds, counted vmcnt, barrier, MFMA m4-7 ----
#pragma unroll
    for (int m = 0; m < 4; ++m) af[4 + m] = *(const bf16x8*)&cb[aoff + (4 + m) * 512];
    if (st) {
      stageB(kt + 2, sbuf);
      asm volatile("s_waitcnt vmcnt(4)" ::: "memory");
      __builtin_amdgcn_s_barrier();
    } else if (kt + 1 < NT) {
      asm volatile("s_waitcnt vmcnt(0)" ::: "memory");
      __builtin_amdgcn_s_barrier();
    }
    __builtin_amdgcn_s_setprio(1);
#pragma unroll
    for (int m = 0; m < 4; ++m)
#pragma unroll
      for (int n = 0; n < 4; ++n)
        acc[4 + m][n] = __builtin_amdgcn_mfma_f32_16x16x32_bf16(af[4 + m], bfv[n], acc[4 + m][n], 0, 0, 0);
    __builtin_amdgcn_s_setprio(0);
    cbuf = nbuf;
  }

  if (OUTBF == 3) {
    // fused RoPE + QKV split epilogue. Tile is entirely Q (col0<1024), K, or V.
    // Q is pre-scaled by 1/8 (exact) so attn skips the scale multiply.
    const int reg = col0 >> 10;
    const int fb = col0 & 1023;
#pragma unroll
    for (int m = 0; m < 8; ++m) {
      const int row = row0 + wr * 128 + m * 16 + lg * 4;
      const int b = row >> 11, tbase = row & 2047;
      if (reg < 2) {
        u16* dstp = (reg == 0) ? Qb : Kb;
        const float qs = (reg == 0) ? 0.125f : 1.0f;
#pragma unroll
        for (int n = 0; n < 2; ++n) {
          const int f = fb + wc * 64 + n * 16 + l15;
          const int h = f >> 6, j = f & 63;  // j < 32
#pragma unroll
          for (int r = 0; r < 4; ++r) {
            const int tt = tbase + r;
            const float c = cosT[tt * 32 + j], s = sinT[tt * 32 + j];
            const float x1 = acc[m][n][r], x2 = acc[m][n | 2][r];
            const size_t ro = ((size_t)(b * NHH + h) * TT + tt) * HDD + j;
            dstp[ro] = f2bf((x1 * c - x2 * s) * qs);
            dstp[ro + 32] = f2bf((x1 * s + x2 * c) * qs);
          }
        }
      } else {
#pragma unroll
        for (int n = 0; n < 4; ++n) {
          const int f = fb + wc * 64 + n * 16 + l15;
          const int h = f >> 6, j = f & 63;
          ushort4 pk;
          pk.x = f2bf(acc[m][n][0]);
          pk.y = f2bf(acc[m][n][1]);
          pk.z = f2bf(acc[m][n][2]);
          pk.w = f2bf(acc[m][n][3]);
          *(ushort4*)&Vtb[((size_t)(b * NHH + h) * HDD + j) * TT + tbase] = pk;
        }
      }
    }
    return;
  }

#pragma unroll
  for (int m = 0; m < 8; ++m) {
    const int row = row0 + wr * 128 + m * 16 + lg * 4;
#pragma unroll
    for (int n = 0; n < 4; ++n) {
      const int col = col0 + wc * 64 + n * 16 + l15;
#pragma unroll
      for (int r = 0; r < 4; ++r) {
        const size_t o = (size_t)(row + r) * N + col;
        if (OUTBF == 0) {
          C[o] = acc[m][n][r];
        } else if (OUTBF == 1) {
          C16[o] = f2bf(acc[m][n][r]);
        } else {
          const float g = bf2f(G[o]);
          C16[o] = f2bf(g / (1.0f + __expf(-g)) * acc[m][n][r]);
        }
      }
    }
  }
}

// ---------------- GEMM engine: 128x128, BK=32, 3-buffer ring (residual add), proj/w3 ----------------
// Same reads-before-barrier skeleton, 1 phase per K-tile, 48 KB LDS -> 3 blocks/CU.
__global__ __launch_bounds__(256, 3) void gemm128r(const u16* __restrict__ A,
                                                   const u16* __restrict__ Bw,
                                                   float* __restrict__ C,
                                                   const float* __restrict__ R,
                                                   int N, int K) {
  __shared__ u16 lds[3 * 8192];  // 48 KB
  const int t = threadIdx.x;
  const int lane = t & 63;
  const int wid = t >> 6;
  const int wr = wid >> 1;
  const int wc = wid & 1;
  const int l15 = lane & 15, lg = lane >> 4;
  const int bid = blockIdx.x;
  const int row0 = (bid & 31) << 7;
  const int col0 = (bid >> 5) << 7;
  const int NT = K >> 5;

  const int rA = t >> 2;  // 0..63
  const int usw = (((t & 3) ^ ((t >> 3) & 3)) << 3);
  const u16* sA0 = A + (size_t)(row0 + rA) * K + usw;
  const u16* sA1 = A + (size_t)(row0 + 64 + rA) * K + usw;
  const u16* sB0 = Bw + (size_t)(col0 + rA) * K + usw;
  const u16* sB1 = Bw + (size_t)(col0 + 64 + rA) * K + usw;
  const int dst = t << 3;  // 0..2047

  const int e8 = ((lg ^ ((l15 >> 1) & 3)) << 3);
  const int aoff = (wr * 64 + l15) * 32 + e8;
  const int boff = 4096 + (wc * 64 + l15) * 32 + e8;

  f32x4 acc[4][4] = {};

  auto stage = [&](int kt, int buf) {
    u16* b = &lds[buf * 8192];
    const size_t ko = (size_t)kt * 32;
    __builtin_amdgcn_global_load_lds((const GLOBAL_AS void*)(sA0 + ko),
                                     (LDS_AS void*)(b + dst), 16, 0, 0);
    __builtin_amdgcn_global_load_lds((const GLOBAL_AS void*)(sA1 + ko),
                                     (LDS_AS void*)(b + 2048 + dst), 16, 0, 0);
    __builtin_amdgcn_global_load_lds((const GLOBAL_AS void*)(sB0 + ko),
                                     (LDS_AS void*)(b + 4096 + dst), 16, 0, 0);
    __builtin_amdgcn_global_load_lds((const GLOBAL_AS void*)(sB1 + ko),
                                     (LDS_AS void*)(b + 6144 + dst), 16, 0, 0);
  };

  stage(0, 0);
  stage(1, 1);
  asm volatile("s_waitcnt vmcnt(4)" ::: "memory");
  __builtin_amdgcn_s_barrier();

  int cbuf = 0;
  for (int kt = 0; kt < NT; ++kt) {
    const u16* cb = &lds[cbuf * 8192];
    const int nbuf = (cbuf == 2) ? 0 : cbuf + 1;
    const int sbuf = (nbuf == 2) ? 0 : nbuf + 1;
    bf16x8 af[4], bfv[4];
#pragma unroll
    for (int m = 0; m < 4; ++m) af[m] = *(const bf16x8*)&cb[aoff + m * 512];
#pragma unroll
    for (int n = 0; n < 4; ++n) bfv[n] = *(const bf16x8*)&cb[boff + n * 512];
    if (kt + 2 < NT) {
      stage(kt + 2, sbuf);
      asm volatile("s_waitcnt vmcnt(4)" ::: "memory");
      __builtin_amdgcn_s_barrier();
    } else if (kt + 1 < NT) {
      asm volatile("s_waitcnt vmcnt(0)" ::: "memory");
      __builtin_amdgcn_s_barrier();
    }
    __builtin_amdgcn_s_setprio(1);
#pragma unroll
    for (int m = 0; m < 4; ++m)
#pragma unroll
      for (int n = 0; n < 4; ++n)
        acc[m][n] = __builtin_amdgcn_mfma_f32_16x16x32_bf16(af[m], bfv[n], acc[m][n], 0, 0, 0);
    __builtin_amdgcn_s_setprio(0);
    cbuf = nbuf;
  }

#pragma unroll
  for (int m = 0; m < 4; ++m) {
    const int row = row0 + wr * 64 + m * 16 + lg * 4;
#pragma unroll
    for (int n = 0; n < 4; ++n) {
      const int col = col0 + wc * 64 + n * 16 + l15;
#pragma unroll
      for (int r = 0; r < 4; ++r) {
        const size_t o = (size_t)(row + r) * N + col;
        C[o] = acc[m][n][r] + R[o];
      }
    }
  }
}

// ---------------- attention: flash-style, no-max softmax (Q pre-scaled by 1/8), ----------------
// denominator via MFMA row-sum against an all-ones B operand.
__global__ __launch_bounds__(256) void attn_k(const u16* __restrict__ Q,
                                              const u16* __restrict__ Kc,
                                              const u16* __restrict__ Vt,
                                              u16* __restrict__ O) {
  __shared__ u16 P_lds[4][32][72];
  const int bh = blockIdx.y;
  const int q0 = blockIdx.x * 128;
  const int lane = threadIdx.x & 63;
  const int w = threadIdx.x >> 6;
  const int l15 = lane & 15, lg = lane >> 4;
  const int qbase = q0 + w * 32;

  bf16x8 qf[2][2];
#pragma unroll
  for (int am = 0; am < 2; ++am)
#pragma unroll
    for (int ks = 0; ks < 2; ++ks)
      qf[am][ks] = *(const bf16x8*)&Q[((size_t)bh * TT + qbase + am * 16 + l15) * HDD + ks * 32 + lg * 8];

  bf16x8 ones;
#pragma unroll
  for (int i = 0; i < 8; ++i) ones[i] = (short)0x3F80;  // bf16 1.0

  f32x4 oacc[2][4] = {};
  f32x4 lacc[2] = {};

  const int ntile = (q0 + 128) >> 6;
  for (int kt = 0; kt < ntile; ++kt) {
    const int k0 = kt << 6;
    f32x4 s[2][4];
    bf16x8 kf0[4], kf1[4];
#pragma unroll
    for (int an = 0; an < 4; ++an) {
      kf0[an] = *(const bf16x8*)&Kc[((size_t)bh * TT + k0 + an * 16 + l15) * HDD + lg * 8];
      kf1[an] = *(const bf16x8*)&Kc[((size_t)bh * TT + k0 + an * 16 + l15) * HDD + 32 + lg * 8];
    }
    __builtin_amdgcn_s_setprio(1);
#pragma unroll
    for (int an = 0; an < 4; ++an) {
#pragma unroll
      for (int am = 0; am < 2; ++am) {
        f32x4 z = {0.0f, 0.0f, 0.0f, 0.0f};
        z = __builtin_amdgcn_mfma_f32_16x16x32_bf16(qf[am][0], kf0[an], z, 0, 0, 0);
        s[am][an] = __builtin_amdgcn_mfma_f32_16x16x32_bf16(qf[am][1], kf1[an], z, 0, 0, 0);
      }
    }
    __builtin_amdgcn_s_setprio(0);
    // causal mask + exp (Q pre-scaled; no max subtraction: scores bounded, f32-safe)
    const bool diag = (k0 + 64) > q0;
#pragma unroll
    for (int am = 0; am < 2; ++am)
#pragma unroll
      for (int an = 0; an < 4; ++an)
#pragma unroll
        for (int r = 0; r < 4; ++r) {
          float v = s[am][an][r];
          if (diag) {
            const int qrow = qbase + am * 16 + lg * 4 + r;
            const int kcol = k0 + an * 16 + l15;
            if (kcol > qrow) v = -1e30f;
          }
          s[am][an][r] = __expf(v);
        }
    // P -> LDS (wave-private region), then PV + l-sum MFMA
#pragma unroll
    for (int am = 0; am < 2; ++am)
#pragma unroll
      for (int an = 0; an < 4; ++an)
#pragma unroll
        for (int r = 0; r < 4; ++r)
          P_lds[w][am * 16 + lg * 4 + r][an * 16 + l15] = f2bf(s[am][an][r]);
#pragma unroll
    for (int ks = 0; ks < 2; ++ks) {
      bf16x8 pf[2];
#pragma unroll
      for (int am = 0; am < 2; ++am)
        pf[am] = *(const bf16x8*)&P_lds[w][am * 16 + l15][ks * 32 + lg * 8];
      __builtin_amdgcn_s_setprio(1);
#pragma unroll
      for (int dn = 0; dn < 4; ++dn) {
        const bf16x8 vf = *(const bf16x8*)&Vt[((size_t)bh * HDD + dn * 16 + l15) * TT + k0 + ks * 32 + lg * 8];
#pragma unroll
        for (int am = 0; am < 2; ++am)
          oacc[am][dn] = __builtin_amdgcn_mfma_f32_16x16x32_bf16(pf[am], vf, oacc[am][dn], 0, 0, 0);
      }
#pragma unroll
      for (int am = 0; am < 2; ++am)
        lacc[am] = __builtin_amdgcn_mfma_f32_16x16x32_bf16(pf[am], ones, lacc[am], 0, 0, 0);
      __builtin_amdgcn_s_setprio(0);
    }
  }
  const int b = bh >> 4, h = bh & 15;
#pragma unroll
  for (int am = 0; am < 2; ++am)
#pragma unroll
    for (int r = 0; r < 4; ++r) {
      const float il = 1.0f / lacc[am][r];
      const int qrow = qbase + am * 16 + lg * 4 + r;
#pragma unroll
      for (int dn = 0; dn < 4; ++dn)
        O[((size_t)b * TT + qrow) * EE + h * 64 + dn * 16 + l15] = f2bf(oacc[am][dn][r] * il);
    }
}

// ---------------- host ----------------

extern "C" void kernel_launch(void* const* d_in, const int* in_sizes, int n_in,
                              void* d_out, int out_size, void* d_ws, size_t ws_size,
                              hipStream_t stream) {
  const int* idx = (const int*)d_in[0];
  const float* tok_emb = (const float*)d_in[1];
  const float* qkv_w = (const float*)d_in[2];
  const float* proj_w = (const float*)d_in[3];
  const float* w1 = (const float*)d_in[4];
  const float* w2 = (const float*)d_in[5];
  const float* w3 = (const float*)d_in[6];
  const float* norm1_w = (const float*)d_in[7];
  const float* norm2_w = (const float*)d_in[8];
  const float* norm_f_w = (const float*)d_in[9];
  float* out = (float*)d_out;

  char* ws = (char*)d_ws;
  size_t off = 0;
  auto alloc = [&](size_t bytes) -> void* {
    off = (off + 255) & ~(size_t)255;
    void* p = ws + off;
    off += bytes;
    return p;
  };

  const size_t N_TEMB = (size_t)VV * EE;
  const size_t N_QKVW = (size_t)8 * 3 * EE * EE;
  const size_t N_PROJW = (size_t)8 * EE * EE;
  const size_t N_W1 = (size_t)8 * HIDD * EE;
  const size_t N_W3 = (size_t)8 * EE * HIDD;

  u16* tembbf = (u16*)alloc(N_TEMB * 2);
  u16* qkvwbf = (u16*)alloc(N_QKVW * 2);
  u16* projwbf = (u16*)alloc(N_PROJW * 2);
  u16* w1bf = (u16*)alloc(N_W1 * 2);
  u16* w2bf = (u16*)alloc(N_W1 * 2);
  u16* w3bf = (u16*)alloc(N_W3 * 2);
  float* x = (float*)alloc((size_t)MM * EE * 4);
  u16* h1 = (u16*)alloc((size_t)MM * EE * 2);
  u16* hg = (u16*)alloc((size_t)MM * HIDD * 2);
  u16* qb = (u16*)alloc((size_t)2 * NHH * TT * HDD * 2);
  u16* kb = (u16*)alloc((size_t)2 * NHH * TT * HDD * 2);
  u16* vtb = (u16*)alloc((size_t)2 * NHH * TT * HDD * 2);
  u16* attno = (u16*)alloc((size_t)MM * EE * 2);
  float* cosT = (float*)alloc((size_t)TT * 32 * 4);
  float* sinT = (float*)alloc((size_t)TT * 32 * 4);

  // bf16 scratch inside d_out (fully rewritten by final GEMM)
  u16* g16 = (u16*)(out + 16777216);            // 4096*2816 bf16

  auto cast = [&](const float* src, u16* dst, size_t n) {
    const long n4 = (long)(n / 4);
    castbf_k<<<(int)((n4 + 255) / 256), 256, 0, stream>>>(src, dst, n4);
  };
  cast(tok_emb, tembbf, N_TEMB);
  cast(qkv_w, qkvwbf, N_QKVW);
  cast(proj_w, projwbf, N_PROJW);
  cast(w1, w1bf, N_W1);
  cast(w2, w2bf, N_W1);
  cast(w3, w3bf, N_W3);

  ropetab_k<<<TT, 32, 0, stream>>>(cosT, sinT);
  embed_k<<<MM, 256, 0, stream>>>(idx, tok_emb, x);

  for (int l = 0; l < 8; ++l) {
    rmsnorm_k<<<MM, 256, 0, stream>>>(x, norm1_w + l * EE, h1);
    gemm256p<3, 0><<<dim3(12 * 16), 512, 0, stream>>>(h1, qkvwbf + (size_t)l * 3 * EE * EE,
                                                      nullptr, nullptr, nullptr,
                                                      cosT, sinT, qb, kb, vtb, 3 * EE, EE);
    attn_k<<<dim3(16, 32), 256, 0, stream>>>(qb, kb, vtb, attno);
    gemm128r<<<dim3(8 * 32), 256, 0, stream>>>(attno, projwbf + (size_t)l * EE * EE,
                                               x, x, EE, EE);
    rmsnorm_k<<<MM, 256, 0, stream>>>(x, norm2_w + l * EE, h1);
    gemm256p<1, 0><<<dim3(11 * 16), 512, 0, stream>>>(h1, w1bf + (size_t)l * HIDD * EE,
                                                      nullptr, g16, nullptr,
                                                      nullptr, nullptr, nullptr, nullptr, nullptr,
                                                      HIDD, EE);
    gemm256p<2, 0><<<dim3(11 * 16), 512, 0, stream>>>(h1, w2bf + (size_t)l * HIDD * EE,
                                                      nullptr, hg, g16,
                                                      nullptr, nullptr, nullptr, nullptr, nullptr,
                                                      HIDD, EE);
    gemm128r<<<dim3(8 * 32), 256, 0, stream>>>(hg, w3bf + (size_t)l * EE * HIDD,
                                               x, x, EE, HIDD);
  }
  rmsnorm_k<<<MM, 256, 0, stream>>>(x, norm_f_w, h1);
  // logits: XCD-grouped swizzle, grid padded to 128 col-tiles (early-exit beyond 125)
  gemm256p<0, 1><<<dim3(128 * 16), 512, 0, stream>>>(h1, tembbf, out, nullptr, nullptr,
                                                     nullptr, nullptr, nullptr, nullptr, nullptr,
                                                     VV, EE);
}

// Round 8
// 2741.412 us; speedup vs baseline: 1.0657x; 1.0657x over previous
//
#include <hip/hip_runtime.h>

#define GLOBAL_AS __attribute__((address_space(1)))
#define LDS_AS __attribute__((address_space(3)))

typedef unsigned short u16;
typedef unsigned int u32;
typedef __attribute__((ext_vector_type(4))) float f32x4;
typedef __attribute__((ext_vector_type(8))) short bf16x8;

// Model dims
#define TT 2048
#define EE 1024
#define NHH 16
#define HDD 64
#define HIDD 2816
#define VV 32000
#define MM 4096   // B*T

__device__ __forceinline__ u16 f2bf(float f) {
  u32 u = __builtin_bit_cast(u32, f);
  u += 0x7fffu + ((u >> 16) & 1u);
  return (u16)(u >> 16);
}
__device__ __forceinline__ float bf2f(u16 v) {
  return __builtin_bit_cast(float, (u32)v << 16);
}

// ---------------- elementwise / staging kernels ----------------

__global__ __launch_bounds__(256) void castbf_k(const float* __restrict__ in,
                                                u16* __restrict__ o, long n4) {
  const long i = (long)blockIdx.x * 256 + threadIdx.x;
  if (i >= n4) return;
  const float4 v = ((const float4*)in)[i];
  ((uint2*)o)[i] = make_uint2((u32)f2bf(v.x) | ((u32)f2bf(v.y) << 16),
                              (u32)f2bf(v.z) | ((u32)f2bf(v.w) << 16));
}

__global__ void ropetab_k(float* __restrict__ cosT, float* __restrict__ sinT) {
  const int t = blockIdx.x, j = threadIdx.x;  // j in [0,32)
  const float inv = powf(10000.0f, -(float)j * (1.0f / 32.0f));
  const float f = (float)t * inv;
  cosT[t * 32 + j] = cosf(f);
  sinT[t * 32 + j] = sinf(f);
}

__global__ __launch_bounds__(256) void embed_k(const int* __restrict__ idx,
                                               const float* __restrict__ temb,
                                               float* __restrict__ x) {
  const int row = blockIdx.x;
  const int id = idx[row];
  ((float4*)(x + (size_t)row * EE))[threadIdx.x] =
      ((const float4*)(temb + (size_t)id * EE))[threadIdx.x];
}

__global__ __launch_bounds__(256) void rmsnorm_k(const float* __restrict__ x,
                                                 const float* __restrict__ w,
                                                 u16* __restrict__ o) {
  __shared__ float red[4];
  const int row = blockIdx.x, tid = threadIdx.x;
  const float4 v = ((const float4*)(x + (size_t)row * EE))[tid];
  float ss = v.x * v.x + v.y * v.y + v.z * v.z + v.w * v.w;
#pragma unroll
  for (int off = 32; off; off >>= 1) ss += __shfl_xor(ss, off, 64);
  if ((tid & 63) == 0) red[tid >> 6] = ss;
  __syncthreads();
  const float inv = rsqrtf((red[0] + red[1] + red[2] + red[3]) * (1.0f / 1024.0f) + 1e-6f);
  const float4 wv = ((const float4*)w)[tid];
  const u32 lo = (u32)f2bf(v.x * inv * wv.x) | ((u32)f2bf(v.y * inv * wv.y) << 16);
  const u32 hi = (u32)f2bf(v.z * inv * wv.z) | ((u32)f2bf(v.w * inv * wv.w) << 16);
  ((uint2*)(o + (size_t)row * EE))[tid] = make_uint2(lo, hi);
}

// ---------------- GEMM engine: 256x256, BK=64, 4-phase counted-vmcnt dbuf (R5 engine) ----------------
// C[M,N] = A[M,K] * B[N,K]^T, bf16 in, f32 accum. M = 4096, K multiple of 64.
// 8 waves (wr 0..1 x wc 0..3), per-wave 128x64 output. LDS 2 x 64KB buffers.
// Per K-tile: 4 phases {vmcnt(4); barrier; ds_read quadrant; issue 2 glds for kt+1;
// setprio(1) 16xMFMA setprio(0)}. Load order matches phase consumption -> steady vmcnt(4).
// B rows permuted nh-major in LDS. Unit swizzle: 16B-unit ^= (row&7), both sides.
// OUTBF: 0 f32 C ; 1 bf16 C16 ; 2 C16 = silu(G)*acc ; 3 rope-split -> Qb/Kb/Vtb (Q pre-scaled 1/8).
template <int OUTBF>
__global__ __launch_bounds__(512, 2) void gemm256p(const u16* __restrict__ A,
                                                   const u16* __restrict__ Bw,
                                                   float* __restrict__ C,
                                                   u16* __restrict__ C16,
                                                   const u16* __restrict__ G,
                                                   const float* __restrict__ cosT,
                                                   const float* __restrict__ sinT,
                                                   u16* __restrict__ Qb,
                                                   u16* __restrict__ Kb,
                                                   u16* __restrict__ Vtb,
                                                   int N, int K) {
  __shared__ u16 lds[2 * 32768];  // 128 KB
  const int t = threadIdx.x;
  const int lane = t & 63;
  const int wid = t >> 6;
  const int wr = wid >> 2;   // 0..1
  const int wc = wid & 3;    // 0..3
  const int l15 = lane & 15, lg = lane >> 4;
  const int bid = blockIdx.x;
  const int row0 = (bid & 15) << 8;
  const int col0 = (bid >> 4) << 8;
  const int NT = K >> 6;

  // staging geometry: group = 64 rows x 128B; thread t -> row sr=t>>3, unit t&7
  const int sr = t >> 3;
  const int su8 = (((t & 7) ^ (sr & 7)) << 3);  // pre-swizzled global elem offset
  const int t8 = t << 3;
  const u16* aG[4];
#pragma unroll
  for (int ga = 0; ga < 4; ++ga)
    aG[ga] = A + (size_t)(row0 + ga * 64 + sr) * K + su8;
  const u16* bG[4];
#pragma unroll
  for (int gb = 0; gb < 4; ++gb) {
    const int q = (gb * 2 + (sr >> 5)) & 3;
    const int nh = gb >> 1;
    bG[gb] = Bw + (size_t)(col0 + q * 64 + nh * 32 + (sr & 31)) * K + su8;
  }

  // fragment read offsets (u16 elems)
  const int u0 = ((lg ^ (l15 & 7)) << 3);          // ks=0 unit
  const int u1 = (((4 | lg) ^ (l15 & 7)) << 3);    // ks=1 unit
  const int arow = (wr * 128 + l15) << 6;          // + m*1024
  const int brow = 16384 + ((wc * 32 + l15) << 6); // + nh*8192 + ni*1024

  f32x4 acc[8][4] = {};

#define STA(nb, ga, k0n)                                                              \
  __builtin_amdgcn_global_load_lds((const GLOBAL_AS void*)(aG[ga] + (k0n)),           \
                                   (LDS_AS void*)((nb) + (ga)*4096 + t8), 16, 0, 0)
#define STB(nb, gb, k0n)                                                              \
  __builtin_amdgcn_global_load_lds((const GLOBAL_AS void*)(bG[gb] + (k0n)),           \
                                   (LDS_AS void*)((nb) + 16384 + (gb)*4096 + t8), 16, 0, 0)

  // prologue: stage kt=0 in consumption order
  {
    u16* nb = lds;
    STA(nb, 0, 0); STA(nb, 2, 0);
    STB(nb, 0, 0); STB(nb, 1, 0);
    STB(nb, 2, 0); STB(nb, 3, 0);
    STA(nb, 1, 0); STA(nb, 3, 0);
  }

  bf16x8 af[4][2], bl[2][2], bh[2][2];

  for (int kt = 0; kt < NT; ++kt) {
    const bool st = (kt + 1 < NT);
    const int k0n = (kt + 1) << 6;
    const u16* cb = lds + (kt & 1) * 32768;
    u16* nb = lds + ((kt + 1) & 1) * 32768;

    // ---- phase 0: mh=0, nh=0 ----
    asm volatile("s_waitcnt vmcnt(4)" ::: "memory");
    __builtin_amdgcn_s_barrier();
#pragma unroll
    for (int mi = 0; mi < 4; ++mi) {
      af[mi][0] = *(const bf16x8*)&cb[arow + mi * 1024 + u0];
      af[mi][1] = *(const bf16x8*)&cb[arow + mi * 1024 + u1];
    }
#pragma unroll
    for (int ni = 0; ni < 2; ++ni) {
      bl[ni][0] = *(const bf16x8*)&cb[brow + ni * 1024 + u0];
      bl[ni][1] = *(const bf16x8*)&cb[brow + ni * 1024 + u1];
    }
    if (st) { STA(nb, 0, k0n); STA(nb, 2, k0n); }
    __builtin_amdgcn_s_setprio(1);
#pragma unroll
    for (int mi = 0; mi < 4; ++mi)
#pragma unroll
      for (int ni = 0; ni < 2; ++ni) {
        acc[mi][ni] = __builtin_amdgcn_mfma_f32_16x16x32_bf16(af[mi][0], bl[ni][0], acc[mi][ni], 0, 0, 0);
        acc[mi][ni] = __builtin_amdgcn_mfma_f32_16x16x32_bf16(af[mi][1], bl[ni][1], acc[mi][ni], 0, 0, 0);
      }
    __builtin_amdgcn_s_setprio(0);

    // ---- phase 1: mh=0, nh=1 ----
    if (st) { asm volatile("s_waitcnt vmcnt(4)" ::: "memory"); }
    else    { asm volatile("s_waitcnt vmcnt(2)" ::: "memory"); }
    __builtin_amdgcn_s_barrier();
#pragma unroll
    for (int ni = 0; ni < 2; ++ni) {
      bh[ni][0] = *(const bf16x8*)&cb[brow + 8192 + ni * 1024 + u0];
      bh[ni][1] = *(const bf16x8*)&cb[brow + 8192 + ni * 1024 + u1];
    }
    if (st) { STB(nb, 0, k0n); STB(nb, 1, k0n); }
    __builtin_amdgcn_s_setprio(1);
#pragma unroll
    for (int mi = 0; mi < 4; ++mi)
#pragma unroll
      for (int ni = 0; ni < 2; ++ni) {
        acc[mi][2 + ni] = __builtin_amdgcn_mfma_f32_16x16x32_bf16(af[mi][0], bh[ni][0], acc[mi][2 + ni], 0, 0, 0);
        acc[mi][2 + ni] = __builtin_amdgcn_mfma_f32_16x16x32_bf16(af[mi][1], bh[ni][1], acc[mi][2 + ni], 0, 0, 0);
      }
    __builtin_amdgcn_s_setprio(0);

    // ---- phase 2: mh=1, nh=1 ----
    if (st) { asm volatile("s_waitcnt vmcnt(4)" ::: "memory"); }
    else    { asm volatile("s_waitcnt vmcnt(0)" ::: "memory"); }
    __builtin_amdgcn_s_barrier();
#pragma unroll
    for (int mi = 0; mi < 4; ++mi) {
      af[mi][0] = *(const bf16x8*)&cb[arow + (4 + mi) * 1024 + u0];
      af[mi][1] = *(const bf16x8*)&cb[arow + (4 + mi) * 1024 + u1];
    }
    if (st) { STB(nb, 2, k0n); STB(nb, 3, k0n); }
    __builtin_amdgcn_s_setprio(1);
#pragma unroll
    for (int mi = 0; mi < 4; ++mi)
#pragma unroll
      for (int ni = 0; ni < 2; ++ni) {
        acc[4 + mi][2 + ni] = __builtin_amdgcn_mfma_f32_16x16x32_bf16(af[mi][0], bh[ni][0], acc[4 + mi][2 + ni], 0, 0, 0);
        acc[4 + mi][2 + ni] = __builtin_amdgcn_mfma_f32_16x16x32_bf16(af[mi][1], bh[ni][1], acc[4 + mi][2 + ni], 0, 0, 0);
      }
    __builtin_amdgcn_s_setprio(0);

    // ---- phase 3: mh=1, nh=0 (no new reads) ----
    if (st) { STA(nb, 1, k0n); STA(nb, 3, k0n); }
    __builtin_amdgcn_s_setprio(1);
#pragma unroll
    for (int mi = 0; mi < 4; ++mi)
#pragma unroll
      for (int ni = 0; ni < 2; ++ni) {
        acc[4 + mi][ni] = __builtin_amdgcn_mfma_f32_16x16x32_bf16(af[mi][0], bl[ni][0], acc[4 + mi][ni], 0, 0, 0);
        acc[4 + mi][ni] = __builtin_amdgcn_mfma_f32_16x16x32_bf16(af[mi][1], bl[ni][1], acc[4 + mi][ni], 0, 0, 0);
      }
    __builtin_amdgcn_s_setprio(0);
  }
#undef STA
#undef STB

  if (OUTBF == 3) {
    // fused RoPE + QKV split epilogue. Tile is entirely Q (col0<1024), K, or V.
    // Q pre-scaled by 1/8 (exact) so attn skips the scale multiply.
    const int reg = col0 >> 10;
    const int fb = col0 & 1023;
#pragma unroll
    for (int m = 0; m < 8; ++m) {
      const int row = row0 + wr * 128 + m * 16 + lg * 4;
      const int b = row >> 11, tbase = row & 2047;
      if (reg < 2) {
        u16* dstp = (reg == 0) ? Qb : Kb;
        const float qs = (reg == 0) ? 0.125f : 1.0f;
#pragma unroll
        for (int n = 0; n < 2; ++n) {
          const int f = fb + wc * 64 + n * 16 + l15;
          const int h = f >> 6, j = f & 63;  // j < 32
#pragma unroll
          for (int r = 0; r < 4; ++r) {
            const int tt = tbase + r;
            const float c = cosT[tt * 32 + j], s = sinT[tt * 32 + j];
            const float x1 = acc[m][n][r], x2 = acc[m][n | 2][r];
            const size_t ro = ((size_t)(b * NHH + h) * TT + tt) * HDD + j;
            dstp[ro] = f2bf((x1 * c - x2 * s) * qs);
            dstp[ro + 32] = f2bf((x1 * s + x2 * c) * qs);
          }
        }
      } else {
#pragma unroll
        for (int n = 0; n < 4; ++n) {
          const int f = fb + wc * 64 + n * 16 + l15;
          const int h = f >> 6, j = f & 63;
          ushort4 pk;
          pk.x = f2bf(acc[m][n][0]);
          pk.y = f2bf(acc[m][n][1]);
          pk.z = f2bf(acc[m][n][2]);
          pk.w = f2bf(acc[m][n][3]);
          *(ushort4*)&Vtb[((size_t)(b * NHH + h) * HDD + j) * TT + tbase] = pk;
        }
      }
    }
    return;
  }

#pragma unroll
  for (int m = 0; m < 8; ++m) {
    const int row = row0 + wr * 128 + m * 16 + lg * 4;
#pragma unroll
    for (int n = 0; n < 4; ++n) {
      const int col = col0 + wc * 64 + n * 16 + l15;
#pragma unroll
      for (int r = 0; r < 4; ++r) {
        const size_t o = (size_t)(row + r) * N + col;
        if (OUTBF == 0) {
          C[o] = acc[m][n][r];
        } else if (OUTBF == 1) {
          C16[o] = f2bf(acc[m][n][r]);
        } else {
          const float g = bf2f(G[o]);
          C16[o] = f2bf(g / (1.0f + __expf(-g)) * acc[m][n][r]);
        }
      }
    }
  }
}

// ---------------- GEMM engine: 128x128 ring (residual add), 8 waves, for proj/w3 ----------------
// R5 ring schedule (4-buf, depth-3, counted vmcnt) but 512 threads = 2 waves/SIMD
// so ds_read/barrier latency is hidden by TLP (grid == CU count -> 1 block/CU).
// Wave-tile 2(m) x 4(n): per-wave 64x32 output, acc[4][2]. Stage = 2 glds/tile.
__global__ __launch_bounds__(512, 2) void gemm128r(const u16* __restrict__ A,
                                                   const u16* __restrict__ Bw,
                                                   float* __restrict__ C,
                                                   const float* __restrict__ R,
                                                   int N, int K) {
  __shared__ u16 lds[4 * 8192];  // 64 KB: 4 buffers x (A 128x32 | B 128x32)
  const int t = threadIdx.x;
  const int lane = t & 63;
  const int wid = t >> 6;
  const int wr = wid >> 2;   // 0..1 : 64-row half
  const int wc = wid & 3;    // 0..3 : 32-col quarter
  const int l15 = lane & 15, lg = lane >> 4;
  const int bid = blockIdx.x;
  const int row0 = (bid & 31) << 7;
  const int col0 = (bid >> 5) << 7;
  const int NT = K >> 5;

  const int rA = t >> 2;  // 0..127
  const int usw = (((t & 3) ^ ((t >> 3) & 3)) << 3);
  const u16* sA = A + (size_t)(row0 + rA) * K + usw;
  const u16* sB = Bw + (size_t)(col0 + rA) * K + usw;
  const int dst = t << 3;  // 0..4095

  const int e8 = ((lg ^ ((l15 >> 1) & 3)) << 3);
  const int aoff = (wr * 64 + l15) * 32 + e8;
  const int boff = 4096 + (wc * 32 + l15) * 32 + e8;

  f32x4 acc[4][2] = {};

  auto stage = [&](int kt) {
    u16* base = &lds[(kt & 3) * 8192];
    const size_t ko = (size_t)kt * 32;
    __builtin_amdgcn_global_load_lds((const GLOBAL_AS void*)(sA + ko),
                                     (LDS_AS void*)(base + dst), 16, 0, 0);
    __builtin_amdgcn_global_load_lds((const GLOBAL_AS void*)(sB + ko),
                                     (LDS_AS void*)(base + 4096 + dst), 16, 0, 0);
  };

  stage(0);
  stage(1);
  stage(2);

  for (int kt = 0; kt < NT; ++kt) {
    const int rem = NT - 1 - kt;
    if (rem >= 2) {
      asm volatile("s_waitcnt vmcnt(4)" ::: "memory");
    } else if (rem == 1) {
      asm volatile("s_waitcnt vmcnt(2)" ::: "memory");
    } else {
      asm volatile("s_waitcnt vmcnt(0)" ::: "memory");
    }
    __builtin_amdgcn_s_barrier();
    if (kt + 3 < NT) stage(kt + 3);
    const u16* base = &lds[(kt & 3) * 8192];
    bf16x8 af[4], bfv[2];
#pragma unroll
    for (int m = 0; m < 4; ++m) af[m] = *(const bf16x8*)&base[aoff + m * 512];
#pragma unroll
    for (int n = 0; n < 2; ++n) bfv[n] = *(const bf16x8*)&base[boff + n * 512];
    __builtin_amdgcn_s_setprio(1);
#pragma unroll
    for (int m = 0; m < 4; ++m)
#pragma unroll
      for (int n = 0; n < 2; ++n)
        acc[m][n] = __builtin_amdgcn_mfma_f32_16x16x32_bf16(af[m], bfv[n], acc[m][n], 0, 0, 0);
    __builtin_amdgcn_s_setprio(0);
  }

#pragma unroll
  for (int m = 0; m < 4; ++m) {
    const int row = row0 + wr * 64 + m * 16 + lg * 4;
#pragma unroll
    for (int n = 0; n < 2; ++n) {
      const int col = col0 + wc * 32 + n * 16 + l15;
#pragma unroll
      for (int r = 0; r < 4; ++r) {
        const size_t o = (size_t)(row + r) * N + col;
        C[o] = acc[m][n][r] + R[o];
      }
    }
  }
}

// ---------------- attention: flash-style, no-max softmax (Q pre-scaled by 1/8), ----------------
// denominator via MFMA row-sum against an all-ones B operand.
__global__ __launch_bounds__(256) void attn_k(const u16* __restrict__ Q,
                                              const u16* __restrict__ Kc,
                                              const u16* __restrict__ Vt,
                                              u16* __restrict__ O) {
  __shared__ u16 P_lds[4][32][72];
  const int bh = blockIdx.y;
  const int q0 = blockIdx.x * 128;
  const int lane = threadIdx.x & 63;
  const int w = threadIdx.x >> 6;
  const int l15 = lane & 15, lg = lane >> 4;
  const int qbase = q0 + w * 32;

  bf16x8 qf[2][2];
#pragma unroll
  for (int am = 0; am < 2; ++am)
#pragma unroll
    for (int ks = 0; ks < 2; ++ks)
      qf[am][ks] = *(const bf16x8*)&Q[((size_t)bh * TT + qbase + am * 16 + l15) * HDD + ks * 32 + lg * 8];

  bf16x8 ones;
#pragma unroll
  for (int i = 0; i < 8; ++i) ones[i] = (short)0x3F80;  // bf16 1.0

  f32x4 oacc[2][4] = {};
  f32x4 lacc[2] = {};

  const int ntile = (q0 + 128) >> 6;
  for (int kt = 0; kt < ntile; ++kt) {
    const int k0 = kt << 6;
    f32x4 s[2][4];
    bf16x8 kf0[4], kf1[4];
#pragma unroll
    for (int an = 0; an < 4; ++an) {
      kf0[an] = *(const bf16x8*)&Kc[((size_t)bh * TT + k0 + an * 16 + l15) * HDD + lg * 8];
      kf1[an] = *(const bf16x8*)&Kc[((size_t)bh * TT + k0 + an * 16 + l15) * HDD + 32 + lg * 8];
    }
    __builtin_amdgcn_s_setprio(1);
#pragma unroll
    for (int an = 0; an < 4; ++an) {
#pragma unroll
      for (int am = 0; am < 2; ++am) {
        f32x4 z = {0.0f, 0.0f, 0.0f, 0.0f};
        z = __builtin_amdgcn_mfma_f32_16x16x32_bf16(qf[am][0], kf0[an], z, 0, 0, 0);
        s[am][an] = __builtin_amdgcn_mfma_f32_16x16x32_bf16(qf[am][1], kf1[an], z, 0, 0, 0);
      }
    }
    __builtin_amdgcn_s_setprio(0);
    // causal mask + exp (Q pre-scaled; no max subtraction: scores bounded, f32-safe)
    const bool diag = (k0 + 64) > q0;
#pragma unroll
    for (int am = 0; am < 2; ++am)
#pragma unroll
      for (int an = 0; an < 4; ++an)
#pragma unroll
        for (int r = 0; r < 4; ++r) {
          float v = s[am][an][r];
          if (diag) {
            const int qrow = qbase + am * 16 + lg * 4 + r;
            const int kcol = k0 + an * 16 + l15;
            if (kcol > qrow) v = -1e30f;
          }
          s[am][an][r] = __expf(v);
        }
    // P -> LDS (wave-private region), then PV + l-sum MFMA
#pragma unroll
    for (int am = 0; am < 2; ++am)
#pragma unroll
      for (int an = 0; an < 4; ++an)
#pragma unroll
        for (int r = 0; r < 4; ++r)
          P_lds[w][am * 16 + lg * 4 + r][an * 16 + l15] = f2bf(s[am][an][r]);
#pragma unroll
    for (int ks = 0; ks < 2; ++ks) {
      bf16x8 pf[2];
#pragma unroll
      for (int am = 0; am < 2; ++am)
        pf[am] = *(const bf16x8*)&P_lds[w][am * 16 + l15][ks * 32 + lg * 8];
      __builtin_amdgcn_s_setprio(1);
#pragma unroll
      for (int dn = 0; dn < 4; ++dn) {
        const bf16x8 vf = *(const bf16x8*)&Vt[((size_t)bh * HDD + dn * 16 + l15) * TT + k0 + ks * 32 + lg * 8];
#pragma unroll
        for (int am = 0; am < 2; ++am)
          oacc[am][dn] = __builtin_amdgcn_mfma_f32_16x16x32_bf16(pf[am], vf, oacc[am][dn], 0, 0, 0);
      }
#pragma unroll
      for (int am = 0; am < 2; ++am)
        lacc[am] = __builtin_amdgcn_mfma_f32_16x16x32_bf16(pf[am], ones, lacc[am], 0, 0, 0);
      __builtin_amdgcn_s_setprio(0);
    }
  }
  const int b = bh >> 4, h = bh & 15;
#pragma unroll
  for (int am = 0; am < 2; ++am)
#pragma unroll
    for (int r = 0; r < 4; ++r) {
      const float il = 1.0f / lacc[am][r];
      const int qrow = qbase + am * 16 + lg * 4 + r;
#pragma unroll
      for (int dn = 0; dn < 4; ++dn)
        O[((size_t)b * TT + qrow) * EE + h * 64 + dn * 16 + l15] = f2bf(oacc[am][dn][r] * il);
    }
}

// ---------------- host ----------------

extern "C" void kernel_launch(void* const* d_in, const int* in_sizes, int n_in,
                              void* d_out, int out_size, void* d_ws, size_t ws_size,
                              hipStream_t stream) {
  const int* idx = (const int*)d_in[0];
  const float* tok_emb = (const float*)d_in[1];
  const float* qkv_w = (const float*)d_in[2];
  const float* proj_w = (const float*)d_in[3];
  const float* w1 = (const float*)d_in[4];
  const float* w2 = (const float*)d_in[5];
  const float* w3 = (const float*)d_in[6];
  const float* norm1_w = (const float*)d_in[7];
  const float* norm2_w = (const float*)d_in[8];
  const float* norm_f_w = (const float*)d_in[9];
  float* out = (float*)d_out;

  char* ws = (char*)d_ws;
  size_t off = 0;
  auto alloc = [&](size_t bytes) -> void* {
    off = (off + 255) & ~(size_t)255;
    void* p = ws + off;
    off += bytes;
    return p;
  };

  const size_t N_TEMB = (size_t)VV * EE;
  const size_t N_QKVW = (size_t)8 * 3 * EE * EE;
  const size_t N_PROJW = (size_t)8 * EE * EE;
  const size_t N_W1 = (size_t)8 * HIDD * EE;
  const size_t N_W3 = (size_t)8 * EE * HIDD;

  u16* tembbf = (u16*)alloc(N_TEMB * 2);
  u16* qkvwbf = (u16*)alloc(N_QKVW * 2);
  u16* projwbf = (u16*)alloc(N_PROJW * 2);
  u16* w1bf = (u16*)alloc(N_W1 * 2);
  u16* w2bf = (u16*)alloc(N_W1 * 2);
  u16* w3bf = (u16*)alloc(N_W3 * 2);
  float* x = (float*)alloc((size_t)MM * EE * 4);
  u16* h1 = (u16*)alloc((size_t)MM * EE * 2);
  u16* hg = (u16*)alloc((size_t)MM * HIDD * 2);
  u16* qb = (u16*)alloc((size_t)2 * NHH * TT * HDD * 2);
  u16* kb = (u16*)alloc((size_t)2 * NHH * TT * HDD * 2);
  u16* vtb = (u16*)alloc((size_t)2 * NHH * TT * HDD * 2);
  u16* attno = (u16*)alloc((size_t)MM * EE * 2);
  float* cosT = (float*)alloc((size_t)TT * 32 * 4);
  float* sinT = (float*)alloc((size_t)TT * 32 * 4);

  // bf16 scratch inside d_out (fully rewritten by final GEMM)
  u16* g16 = (u16*)(out + 16777216);            // 4096*2816 bf16

  auto cast = [&](const float* src, u16* dst, size_t n) {
    const long n4 = (long)(n / 4);
    castbf_k<<<(int)((n4 + 255) / 256), 256, 0, stream>>>(src, dst, n4);
  };
  cast(tok_emb, tembbf, N_TEMB);
  cast(qkv_w, qkvwbf, N_QKVW);
  cast(proj_w, projwbf, N_PROJW);
  cast(w1, w1bf, N_W1);
  cast(w2, w2bf, N_W1);
  cast(w3, w3bf, N_W3);

  ropetab_k<<<TT, 32, 0, stream>>>(cosT, sinT);
  embed_k<<<MM, 256, 0, stream>>>(idx, tok_emb, x);

  for (int l = 0; l < 8; ++l) {
    rmsnorm_k<<<MM, 256, 0, stream>>>(x, norm1_w + l * EE, h1);
    gemm256p<3><<<dim3(12 * 16), 512, 0, stream>>>(h1, qkvwbf + (size_t)l * 3 * EE * EE,
                                                   nullptr, nullptr, nullptr,
                                                   cosT, sinT, qb, kb, vtb, 3 * EE, EE);
    attn_k<<<dim3(16, 32), 256, 0, stream>>>(qb, kb, vtb, attno);
    gemm128r<<<dim3(8 * 32), 512, 0, stream>>>(attno, projwbf + (size_t)l * EE * EE,
                                               x, x, EE, EE);
    rmsnorm_k<<<MM, 256, 0, stream>>>(x, norm2_w + l * EE, h1);
    gemm256p<1><<<dim3(11 * 16), 512, 0, stream>>>(h1, w1bf + (size_t)l * HIDD * EE,
                                                   nullptr, g16, nullptr,
                                                   nullptr, nullptr, nullptr, nullptr, nullptr,
                                                   HIDD, EE);
    gemm256p<2><<<dim3(11 * 16), 512, 0, stream>>>(h1, w2bf + (size_t)l * HIDD * EE,
                                                   nullptr, hg, g16,
                                                   nullptr, nullptr, nullptr, nullptr, nullptr,
                                                   HIDD, EE);
    gemm128r<<<dim3(8 * 32), 512, 0, stream>>>(hg, w3bf + (size_t)l * EE * HIDD,
                                               x, x, EE, HIDD);
  }
  rmsnorm_k<<<MM, 256, 0, stream>>>(x, norm_f_w, h1);
  gemm256p<0><<<dim3(125 * 16), 512, 0, stream>>>(h1, tembbf, out, nullptr, nullptr,
                                                  nullptr, nullptr, nullptr, nullptr, nullptr,
                                                  VV, EE);
}

// Round 9
// 2567.975 us; speedup vs baseline: 1.1376x; 1.0675x over previous
//
#include <hip/hip_runtime.h>

#define GLOBAL_AS __attribute__((address_space(1)))
#define LDS_AS __attribute__((address_space(3)))

typedef unsigned short u16;
typedef unsigned int u32;
typedef __attribute__((ext_vector_type(4))) float f32x4;
typedef __attribute__((ext_vector_type(8))) short bf16x8;

// Model dims
#define TT 2048
#define EE 1024
#define NHH 16
#define HDD 64
#define HIDD 2816
#define VV 32000
#define MM 4096   // B*T

__device__ __forceinline__ u16 f2bf(float f) {
  u32 u = __builtin_bit_cast(u32, f);
  u += 0x7fffu + ((u >> 16) & 1u);
  return (u16)(u >> 16);
}
__device__ __forceinline__ float bf2f(u16 v) {
  return __builtin_bit_cast(float, (u32)v << 16);
}

// ---------------- elementwise / staging kernels ----------------

__global__ __launch_bounds__(256) void castbf_k(const float* __restrict__ in,
                                                u16* __restrict__ o, long n4) {
  const long i = (long)blockIdx.x * 256 + threadIdx.x;
  if (i >= n4) return;
  const float4 v = ((const float4*)in)[i];
  ((uint2*)o)[i] = make_uint2((u32)f2bf(v.x) | ((u32)f2bf(v.y) << 16),
                              (u32)f2bf(v.z) | ((u32)f2bf(v.w) << 16));
}

__global__ void ropetab_k(float* __restrict__ cosT, float* __restrict__ sinT) {
  const int t = blockIdx.x, j = threadIdx.x;  // j in [0,32)
  const float inv = powf(10000.0f, -(float)j * (1.0f / 32.0f));
  const float f = (float)t * inv;
  cosT[t * 32 + j] = cosf(f);
  sinT[t * 32 + j] = sinf(f);
}

__global__ __launch_bounds__(256) void embed_k(const int* __restrict__ idx,
                                               const float* __restrict__ temb,
                                               float* __restrict__ x) {
  const int row = blockIdx.x;
  const int id = idx[row];
  ((float4*)(x + (size_t)row * EE))[threadIdx.x] =
      ((const float4*)(temb + (size_t)id * EE))[threadIdx.x];
}

__global__ __launch_bounds__(256) void rmsnorm_k(const float* __restrict__ x,
                                                 const float* __restrict__ w,
                                                 u16* __restrict__ o) {
  __shared__ float red[4];
  const int row = blockIdx.x, tid = threadIdx.x;
  const float4 v = ((const float4*)(x + (size_t)row * EE))[tid];
  float ss = v.x * v.x + v.y * v.y + v.z * v.z + v.w * v.w;
#pragma unroll
  for (int off = 32; off; off >>= 1) ss += __shfl_xor(ss, off, 64);
  if ((tid & 63) == 0) red[tid >> 6] = ss;
  __syncthreads();
  const float inv = rsqrtf((red[0] + red[1] + red[2] + red[3]) * (1.0f / 1024.0f) + 1e-6f);
  const float4 wv = ((const float4*)w)[tid];
  const u32 lo = (u32)f2bf(v.x * inv * wv.x) | ((u32)f2bf(v.y * inv * wv.y) << 16);
  const u32 hi = (u32)f2bf(v.z * inv * wv.z) | ((u32)f2bf(v.w * inv * wv.w) << 16);
  ((uint2*)(o + (size_t)row * EE))[tid] = make_uint2(lo, hi);
}

// ---------------- GEMM engine: 256x256, BK=64, 4-phase counted-vmcnt dbuf (R5 engine) ----------------
// Used for the logits GEMM only (grid 2000 blocks). Best measured schedule (38% MfmaUtil).
template <int OUTBF>
__global__ __launch_bounds__(512, 2) void gemm256p(const u16* __restrict__ A,
                                                   const u16* __restrict__ Bw,
                                                   float* __restrict__ C,
                                                   u16* __restrict__ C16,
                                                   const u16* __restrict__ G,
                                                   int N, int K) {
  __shared__ u16 lds[2 * 32768];  // 128 KB
  const int t = threadIdx.x;
  const int lane = t & 63;
  const int wid = t >> 6;
  const int wr = wid >> 2;   // 0..1
  const int wc = wid & 3;    // 0..3
  const int l15 = lane & 15, lg = lane >> 4;
  const int bid = blockIdx.x;
  const int row0 = (bid & 15) << 8;
  const int col0 = (bid >> 4) << 8;
  const int NT = K >> 6;

  const int sr = t >> 3;
  const int su8 = (((t & 7) ^ (sr & 7)) << 3);  // pre-swizzled global elem offset
  const int t8 = t << 3;
  const u16* aG[4];
#pragma unroll
  for (int ga = 0; ga < 4; ++ga)
    aG[ga] = A + (size_t)(row0 + ga * 64 + sr) * K + su8;
  const u16* bG[4];
#pragma unroll
  for (int gb = 0; gb < 4; ++gb) {
    const int q = (gb * 2 + (sr >> 5)) & 3;
    const int nh = gb >> 1;
    bG[gb] = Bw + (size_t)(col0 + q * 64 + nh * 32 + (sr & 31)) * K + su8;
  }

  const int u0 = ((lg ^ (l15 & 7)) << 3);          // ks=0 unit
  const int u1 = (((4 | lg) ^ (l15 & 7)) << 3);    // ks=1 unit
  const int arow = (wr * 128 + l15) << 6;          // + m*1024
  const int brow = 16384 + ((wc * 32 + l15) << 6); // + nh*8192 + ni*1024

  f32x4 acc[8][4] = {};

#define STA(nb, ga, k0n)                                                              \
  __builtin_amdgcn_global_load_lds((const GLOBAL_AS void*)(aG[ga] + (k0n)),           \
                                   (LDS_AS void*)((nb) + (ga)*4096 + t8), 16, 0, 0)
#define STB(nb, gb, k0n)                                                              \
  __builtin_amdgcn_global_load_lds((const GLOBAL_AS void*)(bG[gb] + (k0n)),           \
                                   (LDS_AS void*)((nb) + 16384 + (gb)*4096 + t8), 16, 0, 0)

  {
    u16* nb = lds;
    STA(nb, 0, 0); STA(nb, 2, 0);
    STB(nb, 0, 0); STB(nb, 1, 0);
    STB(nb, 2, 0); STB(nb, 3, 0);
    STA(nb, 1, 0); STA(nb, 3, 0);
  }

  bf16x8 af[4][2], bl[2][2], bh[2][2];

  for (int kt = 0; kt < NT; ++kt) {
    const bool st = (kt + 1 < NT);
    const int k0n = (kt + 1) << 6;
    const u16* cb = lds + (kt & 1) * 32768;
    u16* nb = lds + ((kt + 1) & 1) * 32768;

    // ---- phase 0: mh=0, nh=0 ----
    asm volatile("s_waitcnt vmcnt(4)" ::: "memory");
    __builtin_amdgcn_s_barrier();
#pragma unroll
    for (int mi = 0; mi < 4; ++mi) {
      af[mi][0] = *(const bf16x8*)&cb[arow + mi * 1024 + u0];
      af[mi][1] = *(const bf16x8*)&cb[arow + mi * 1024 + u1];
    }
#pragma unroll
    for (int ni = 0; ni < 2; ++ni) {
      bl[ni][0] = *(const bf16x8*)&cb[brow + ni * 1024 + u0];
      bl[ni][1] = *(const bf16x8*)&cb[brow + ni * 1024 + u1];
    }
    if (st) { STA(nb, 0, k0n); STA(nb, 2, k0n); }
    __builtin_amdgcn_s_setprio(1);
#pragma unroll
    for (int mi = 0; mi < 4; ++mi)
#pragma unroll
      for (int ni = 0; ni < 2; ++ni) {
        acc[mi][ni] = __builtin_amdgcn_mfma_f32_16x16x32_bf16(af[mi][0], bl[ni][0], acc[mi][ni], 0, 0, 0);
        acc[mi][ni] = __builtin_amdgcn_mfma_f32_16x16x32_bf16(af[mi][1], bl[ni][1], acc[mi][ni], 0, 0, 0);
      }
    __builtin_amdgcn_s_setprio(0);

    // ---- phase 1: mh=0, nh=1 ----
    if (st) { asm volatile("s_waitcnt vmcnt(4)" ::: "memory"); }
    else    { asm volatile("s_waitcnt vmcnt(2)" ::: "memory"); }
    __builtin_amdgcn_s_barrier();
#pragma unroll
    for (int ni = 0; ni < 2; ++ni) {
      bh[ni][0] = *(const bf16x8*)&cb[brow + 8192 + ni * 1024 + u0];
      bh[ni][1] = *(const bf16x8*)&cb[brow + 8192 + ni * 1024 + u1];
    }
    if (st) { STB(nb, 0, k0n); STB(nb, 1, k0n); }
    __builtin_amdgcn_s_setprio(1);
#pragma unroll
    for (int mi = 0; mi < 4; ++mi)
#pragma unroll
      for (int ni = 0; ni < 2; ++ni) {
        acc[mi][2 + ni] = __builtin_amdgcn_mfma_f32_16x16x32_bf16(af[mi][0], bh[ni][0], acc[mi][2 + ni], 0, 0, 0);
        acc[mi][2 + ni] = __builtin_amdgcn_mfma_f32_16x16x32_bf16(af[mi][1], bh[ni][1], acc[mi][2 + ni], 0, 0, 0);
      }
    __builtin_amdgcn_s_setprio(0);

    // ---- phase 2: mh=1, nh=1 ----
    if (st) { asm volatile("s_waitcnt vmcnt(4)" ::: "memory"); }
    else    { asm volatile("s_waitcnt vmcnt(0)" ::: "memory"); }
    __builtin_amdgcn_s_barrier();
#pragma unroll
    for (int mi = 0; mi < 4; ++mi) {
      af[mi][0] = *(const bf16x8*)&cb[arow + (4 + mi) * 1024 + u0];
      af[mi][1] = *(const bf16x8*)&cb[arow + (4 + mi) * 1024 + u1];
    }
    if (st) { STB(nb, 2, k0n); STB(nb, 3, k0n); }
    __builtin_amdgcn_s_setprio(1);
#pragma unroll
    for (int mi = 0; mi < 4; ++mi)
#pragma unroll
      for (int ni = 0; ni < 2; ++ni) {
        acc[4 + mi][2 + ni] = __builtin_amdgcn_mfma_f32_16x16x32_bf16(af[mi][0], bh[ni][0], acc[4 + mi][2 + ni], 0, 0, 0);
        acc[4 + mi][2 + ni] = __builtin_amdgcn_mfma_f32_16x16x32_bf16(af[mi][1], bh[ni][1], acc[4 + mi][2 + ni], 0, 0, 0);
      }
    __builtin_amdgcn_s_setprio(0);

    // ---- phase 3: mh=1, nh=0 (no new reads) ----
    if (st) { STA(nb, 1, k0n); STA(nb, 3, k0n); }
    __builtin_amdgcn_s_setprio(1);
#pragma unroll
    for (int mi = 0; mi < 4; ++mi)
#pragma unroll
      for (int ni = 0; ni < 2; ++ni) {
        acc[4 + mi][ni] = __builtin_amdgcn_mfma_f32_16x16x32_bf16(af[mi][0], bl[ni][0], acc[4 + mi][ni], 0, 0, 0);
        acc[4 + mi][ni] = __builtin_amdgcn_mfma_f32_16x16x32_bf16(af[mi][1], bl[ni][1], acc[4 + mi][ni], 0, 0, 0);
      }
    __builtin_amdgcn_s_setprio(0);
  }
#undef STA
#undef STB

#pragma unroll
  for (int m = 0; m < 8; ++m) {
    const int row = row0 + wr * 128 + m * 16 + lg * 4;
#pragma unroll
    for (int n = 0; n < 4; ++n) {
      const int col = col0 + wc * 64 + n * 16 + l15;
#pragma unroll
      for (int r = 0; r < 4; ++r) {
        const size_t o = (size_t)(row + r) * N + col;
        if (OUTBF == 0) {
          C[o] = acc[m][n][r];
        } else if (OUTBF == 1) {
          C16[o] = f2bf(acc[m][n][r]);
        } else {
          const float g = bf2f(G[o]);
          C16[o] = f2bf(g / (1.0f + __expf(-g)) * acc[m][n][r]);
        }
      }
    }
  }
}

// ---------------- GEMM engine: 128x128, 8 waves (wave-tile 32x64), ring, all epilogues ----------------
// Proven R8 ring schedule: 4-buf LDS ring, depth-3 prefetch, counted vmcnt 4/2/0.
// 8 waves as 4(m-groups of 32 rows) x 2(n-groups of 64 cols): per-wave acc[2][4].
// The 64-col wave span makes the RoPE x1/x2 pairing (acc[m][n] / acc[m][n|2]) wave-local.
// Grids: qkv 768, w1/w2 704, proj/w3 256 blocks -> full CU fill (vs 176-192 of 256-tile).
// OUTBF: 0 f32 C = acc + R ; 1 bf16 C16 ; 2 C16 = silu(G)*acc ; 3 rope-split (Q pre-scaled 1/8).
template <int OUTBF>
__global__ __launch_bounds__(512, 2) void gemm128n(const u16* __restrict__ A,
                                                   const u16* __restrict__ Bw,
                                                   float* __restrict__ C,
                                                   const float* __restrict__ R,
                                                   u16* __restrict__ C16,
                                                   const u16* __restrict__ G,
                                                   const float* __restrict__ cosT,
                                                   const float* __restrict__ sinT,
                                                   u16* __restrict__ Qb,
                                                   u16* __restrict__ Kb,
                                                   u16* __restrict__ Vtb,
                                                   int N, int K) {
  __shared__ u16 lds[4 * 8192];  // 64 KB: 4 buffers x (A 128x32 | B 128x32)
  const int t = threadIdx.x;
  const int lane = t & 63;
  const int wid = t >> 6;
  const int wr = wid & 3;    // 0..3 : 32-row group
  const int wc = wid >> 2;   // 0..1 : 64-col group
  const int l15 = lane & 15, lg = lane >> 4;
  const int bid = blockIdx.x;
  const int row0 = (bid & 31) << 7;
  const int col0 = (bid >> 5) << 7;
  const int NT = K >> 5;

  const int rA = t >> 2;  // 0..127
  const int usw = (((t & 3) ^ ((t >> 3) & 3)) << 3);
  const u16* sA = A + (size_t)(row0 + rA) * K + usw;
  const u16* sB = Bw + (size_t)(col0 + rA) * K + usw;
  const int dst = t << 3;  // 0..4095

  const int e8 = ((lg ^ ((l15 >> 1) & 3)) << 3);
  const int aoff = (wr * 32 + l15) * 32 + e8;
  const int boff = 4096 + (wc * 64 + l15) * 32 + e8;

  f32x4 acc[2][4] = {};

  auto stage = [&](int kt) {
    u16* base = &lds[(kt & 3) * 8192];
    const size_t ko = (size_t)kt * 32;
    __builtin_amdgcn_global_load_lds((const GLOBAL_AS void*)(sA + ko),
                                     (LDS_AS void*)(base + dst), 16, 0, 0);
    __builtin_amdgcn_global_load_lds((const GLOBAL_AS void*)(sB + ko),
                                     (LDS_AS void*)(base + 4096 + dst), 16, 0, 0);
  };

  stage(0);
  stage(1);
  stage(2);

  for (int kt = 0; kt < NT; ++kt) {
    const int rem = NT - 1 - kt;
    if (rem >= 2) {
      asm volatile("s_waitcnt vmcnt(4)" ::: "memory");
    } else if (rem == 1) {
      asm volatile("s_waitcnt vmcnt(2)" ::: "memory");
    } else {
      asm volatile("s_waitcnt vmcnt(0)" ::: "memory");
    }
    __builtin_amdgcn_s_barrier();
    if (kt + 3 < NT) stage(kt + 3);
    const u16* base = &lds[(kt & 3) * 8192];
    bf16x8 af[2], bfv[4];
#pragma unroll
    for (int m = 0; m < 2; ++m) af[m] = *(const bf16x8*)&base[aoff + m * 512];
#pragma unroll
    for (int n = 0; n < 4; ++n) bfv[n] = *(const bf16x8*)&base[boff + n * 512];
    __builtin_amdgcn_s_setprio(1);
#pragma unroll
    for (int m = 0; m < 2; ++m)
#pragma unroll
      for (int n = 0; n < 4; ++n)
        acc[m][n] = __builtin_amdgcn_mfma_f32_16x16x32_bf16(af[m], bfv[n], acc[m][n], 0, 0, 0);
    __builtin_amdgcn_s_setprio(0);
  }

  if (OUTBF == 3) {
    // fused RoPE + QKV split. Tile entirely in Q (col0<1024), K, or V region.
    const int reg = col0 >> 10;
    const int fb = col0 & 1023;
#pragma unroll
    for (int m = 0; m < 2; ++m) {
      const int row = row0 + wr * 32 + m * 16 + lg * 4;
      const int b = row >> 11, tbase = row & 2047;
      if (reg < 2) {
        u16* dstp = (reg == 0) ? Qb : Kb;
        const float qs = (reg == 0) ? 0.125f : 1.0f;
#pragma unroll
        for (int n = 0; n < 2; ++n) {
          const int f = fb + wc * 64 + n * 16 + l15;
          const int h = f >> 6, j = f & 63;  // j < 32
#pragma unroll
          for (int r = 0; r < 4; ++r) {
            const int tt = tbase + r;
            const float c = cosT[tt * 32 + j], s = sinT[tt * 32 + j];
            const float x1 = acc[m][n][r], x2 = acc[m][n | 2][r];
            const size_t ro = ((size_t)(b * NHH + h) * TT + tt) * HDD + j;
            dstp[ro] = f2bf((x1 * c - x2 * s) * qs);
            dstp[ro + 32] = f2bf((x1 * s + x2 * c) * qs);
          }
        }
      } else {
#pragma unroll
        for (int n = 0; n < 4; ++n) {
          const int f = fb + wc * 64 + n * 16 + l15;
          const int h = f >> 6, j = f & 63;
          ushort4 pk;
          pk.x = f2bf(acc[m][n][0]);
          pk.y = f2bf(acc[m][n][1]);
          pk.z = f2bf(acc[m][n][2]);
          pk.w = f2bf(acc[m][n][3]);
          *(ushort4*)&Vtb[((size_t)(b * NHH + h) * HDD + j) * TT + tbase] = pk;
        }
      }
    }
    return;
  }

#pragma unroll
  for (int m = 0; m < 2; ++m) {
    const int row = row0 + wr * 32 + m * 16 + lg * 4;
#pragma unroll
    for (int n = 0; n < 4; ++n) {
      const int col = col0 + wc * 64 + n * 16 + l15;
#pragma unroll
      for (int r = 0; r < 4; ++r) {
        const size_t o = (size_t)(row + r) * N + col;
        if (OUTBF == 0) {
          C[o] = acc[m][n][r] + R[o];
        } else if (OUTBF == 1) {
          C16[o] = f2bf(acc[m][n][r]);
        } else {
          const float g = bf2f(G[o]);
          C16[o] = f2bf(g / (1.0f + __expf(-g)) * acc[m][n][r]);
        }
      }
    }
  }
}

// ---------------- attention: flash-style, no-max softmax (Q pre-scaled by 1/8), ----------------
// denominator via MFMA row-sum. Causal load-balance: block c and c+256 (same CU)
// get complementary q-tiles (j, 15-j) -> uniform 34 k-tiles per CU.
__global__ __launch_bounds__(256) void attn_k(const u16* __restrict__ Q,
                                              const u16* __restrict__ Kc,
                                              const u16* __restrict__ Vt,
                                              u16* __restrict__ O) {
  __shared__ u16 P_lds[4][32][72];
  const int bid = blockIdx.x;           // 512 blocks
  const int bh = bid & 31;
  const int jj = bid >> 5;              // 0..15
  const int qi = (bid < 256) ? jj : 23 - jj;
  const int q0 = qi << 7;
  const int lane = threadIdx.x & 63;
  const int w = threadIdx.x >> 6;
  const int l15 = lane & 15, lg = lane >> 4;
  const int qbase = q0 + w * 32;

  bf16x8 qf[2][2];
#pragma unroll
  for (int am = 0; am < 2; ++am)
#pragma unroll
    for (int ks = 0; ks < 2; ++ks)
      qf[am][ks] = *(const bf16x8*)&Q[((size_t)bh * TT + qbase + am * 16 + l15) * HDD + ks * 32 + lg * 8];

  bf16x8 ones;
#pragma unroll
  for (int i = 0; i < 8; ++i) ones[i] = (short)0x3F80;  // bf16 1.0

  f32x4 oacc[2][4] = {};
  f32x4 lacc[2] = {};

  const int ntile = (q0 + 128) >> 6;
  for (int kt = 0; kt < ntile; ++kt) {
    const int k0 = kt << 6;
    f32x4 s[2][4];
    bf16x8 kf0[4], kf1[4];
#pragma unroll
    for (int an = 0; an < 4; ++an) {
      kf0[an] = *(const bf16x8*)&Kc[((size_t)bh * TT + k0 + an * 16 + l15) * HDD + lg * 8];
      kf1[an] = *(const bf16x8*)&Kc[((size_t)bh * TT + k0 + an * 16 + l15) * HDD + 32 + lg * 8];
    }
    __builtin_amdgcn_s_setprio(1);
#pragma unroll
    for (int an = 0; an < 4; ++an) {
#pragma unroll
      for (int am = 0; am < 2; ++am) {
        f32x4 z = {0.0f, 0.0f, 0.0f, 0.0f};
        z = __builtin_amdgcn_mfma_f32_16x16x32_bf16(qf[am][0], kf0[an], z, 0, 0, 0);
        s[am][an] = __builtin_amdgcn_mfma_f32_16x16x32_bf16(qf[am][1], kf1[an], z, 0, 0, 0);
      }
    }
    __builtin_amdgcn_s_setprio(0);
    // causal mask + exp (Q pre-scaled; no max subtraction: scores bounded, f32-safe)
    const bool diag = (k0 + 64) > q0;
#pragma unroll
    for (int am = 0; am < 2; ++am)
#pragma unroll
      for (int an = 0; an < 4; ++an)
#pragma unroll
        for (int r = 0; r < 4; ++r) {
          float v = s[am][an][r];
          if (diag) {
            const int qrow = qbase + am * 16 + lg * 4 + r;
            const int kcol = k0 + an * 16 + l15;
            if (kcol > qrow) v = -1e30f;
          }
          s[am][an][r] = __expf(v);
        }
    // P -> LDS (wave-private region), then PV + l-sum MFMA
#pragma unroll
    for (int am = 0; am < 2; ++am)
#pragma unroll
      for (int an = 0; an < 4; ++an)
#pragma unroll
        for (int r = 0; r < 4; ++r)
          P_lds[w][am * 16 + lg * 4 + r][an * 16 + l15] = f2bf(s[am][an][r]);
#pragma unroll
    for (int ks = 0; ks < 2; ++ks) {
      bf16x8 pf[2];
#pragma unroll
      for (int am = 0; am < 2; ++am)
        pf[am] = *(const bf16x8*)&P_lds[w][am * 16 + l15][ks * 32 + lg * 8];
      __builtin_amdgcn_s_setprio(1);
#pragma unroll
      for (int dn = 0; dn < 4; ++dn) {
        const bf16x8 vf = *(const bf16x8*)&Vt[((size_t)bh * HDD + dn * 16 + l15) * TT + k0 + ks * 32 + lg * 8];
#pragma unroll
        for (int am = 0; am < 2; ++am)
          oacc[am][dn] = __builtin_amdgcn_mfma_f32_16x16x32_bf16(pf[am], vf, oacc[am][dn], 0, 0, 0);
      }
#pragma unroll
      for (int am = 0; am < 2; ++am)
        lacc[am] = __builtin_amdgcn_mfma_f32_16x16x32_bf16(pf[am], ones, lacc[am], 0, 0, 0);
      __builtin_amdgcn_s_setprio(0);
    }
  }
  const int b = bh >> 4, h = bh & 15;
#pragma unroll
  for (int am = 0; am < 2; ++am)
#pragma unroll
    for (int r = 0; r < 4; ++r) {
      const float il = 1.0f / lacc[am][r];
      const int qrow = qbase + am * 16 + lg * 4 + r;
#pragma unroll
      for (int dn = 0; dn < 4; ++dn)
        O[((size_t)b * TT + qrow) * EE + h * 64 + dn * 16 + l15] = f2bf(oacc[am][dn][r] * il);
    }
}

// ---------------- host ----------------

extern "C" void kernel_launch(void* const* d_in, const int* in_sizes, int n_in,
                              void* d_out, int out_size, void* d_ws, size_t ws_size,
                              hipStream_t stream) {
  const int* idx = (const int*)d_in[0];
  const float* tok_emb = (const float*)d_in[1];
  const float* qkv_w = (const float*)d_in[2];
  const float* proj_w = (const float*)d_in[3];
  const float* w1 = (const float*)d_in[4];
  const float* w2 = (const float*)d_in[5];
  const float* w3 = (const float*)d_in[6];
  const float* norm1_w = (const float*)d_in[7];
  const float* norm2_w = (const float*)d_in[8];
  const float* norm_f_w = (const float*)d_in[9];
  float* out = (float*)d_out;

  char* ws = (char*)d_ws;
  size_t off = 0;
  auto alloc = [&](size_t bytes) -> void* {
    off = (off + 255) & ~(size_t)255;
    void* p = ws + off;
    off += bytes;
    return p;
  };

  const size_t N_TEMB = (size_t)VV * EE;
  const size_t N_QKVW = (size_t)8 * 3 * EE * EE;
  const size_t N_PROJW = (size_t)8 * EE * EE;
  const size_t N_W1 = (size_t)8 * HIDD * EE;
  const size_t N_W3 = (size_t)8 * EE * HIDD;

  u16* tembbf = (u16*)alloc(N_TEMB * 2);
  u16* qkvwbf = (u16*)alloc(N_QKVW * 2);
  u16* projwbf = (u16*)alloc(N_PROJW * 2);
  u16* w1bf = (u16*)alloc(N_W1 * 2);
  u16* w2bf = (u16*)alloc(N_W1 * 2);
  u16* w3bf = (u16*)alloc(N_W3 * 2);
  float* x = (float*)alloc((size_t)MM * EE * 4);
  u16* h1 = (u16*)alloc((size_t)MM * EE * 2);
  u16* hg = (u16*)alloc((size_t)MM * HIDD * 2);
  u16* qb = (u16*)alloc((size_t)2 * NHH * TT * HDD * 2);
  u16* kb = (u16*)alloc((size_t)2 * NHH * TT * HDD * 2);
  u16* vtb = (u16*)alloc((size_t)2 * NHH * TT * HDD * 2);
  u16* attno = (u16*)alloc((size_t)MM * EE * 2);
  float* cosT = (float*)alloc((size_t)TT * 32 * 4);
  float* sinT = (float*)alloc((size_t)TT * 32 * 4);

  // bf16 scratch inside d_out (fully rewritten by final GEMM)
  u16* g16 = (u16*)(out + 16777216);            // 4096*2816 bf16

  auto cast = [&](const float* src, u16* dst, size_t n) {
    const long n4 = (long)(n / 4);
    castbf_k<<<(int)((n4 + 255) / 256), 256, 0, stream>>>(src, dst, n4);
  };
  cast(tok_emb, tembbf, N_TEMB);
  cast(qkv_w, qkvwbf, N_QKVW);
  cast(proj_w, projwbf, N_PROJW);
  cast(w1, w1bf, N_W1);
  cast(w2, w2bf, N_W1);
  cast(w3, w3bf, N_W3);

  ropetab_k<<<TT, 32, 0, stream>>>(cosT, sinT);
  embed_k<<<MM, 256, 0, stream>>>(idx, tok_emb, x);

  for (int l = 0; l < 8; ++l) {
    rmsnorm_k<<<MM, 256, 0, stream>>>(x, norm1_w + l * EE, h1);
    gemm128n<3><<<dim3(24 * 32), 512, 0, stream>>>(h1, qkvwbf + (size_t)l * 3 * EE * EE,
                                                   nullptr, nullptr, nullptr, nullptr,
                                                   cosT, sinT, qb, kb, vtb, 3 * EE, EE);
    attn_k<<<dim3(512), 256, 0, stream>>>(qb, kb, vtb, attno);
    gemm128n<0><<<dim3(8 * 32), 512, 0, stream>>>(attno, projwbf + (size_t)l * EE * EE,
                                                  x, x, nullptr, nullptr,
                                                  nullptr, nullptr, nullptr, nullptr, nullptr,
                                                  EE, EE);
    rmsnorm_k<<<MM, 256, 0, stream>>>(x, norm2_w + l * EE, h1);
    gemm128n<1><<<dim3(22 * 32), 512, 0, stream>>>(h1, w1bf + (size_t)l * HIDD * EE,
                                                   nullptr, nullptr, g16, nullptr,
                                                   nullptr, nullptr, nullptr, nullptr, nullptr,
                                                   HIDD, EE);
    gemm128n<2><<<dim3(22 * 32), 512, 0, stream>>>(h1, w2bf + (size_t)l * HIDD * EE,
                                                   nullptr, nullptr, hg, g16,
                                                   nullptr, nullptr, nullptr, nullptr, nullptr,
                                                   HIDD, EE);
    gemm128n<0><<<dim3(8 * 32), 512, 0, stream>>>(hg, w3bf + (size_t)l * EE * HIDD,
                                                  x, x, nullptr, nullptr,
                                                  nullptr, nullptr, nullptr, nullptr, nullptr,
                                                  EE, HIDD);
  }
  rmsnorm_k<<<MM, 256, 0, stream>>>(x, norm_f_w, h1);
  gemm256p<0><<<dim3(125 * 16), 512, 0, stream>>>(h1, tembbf, out, nullptr, nullptr,
                                                  VV, EE);
}

// Round 10
// 2413.754 us; speedup vs baseline: 1.2103x; 1.0639x over previous
//
#include <hip/hip_runtime.h>

#define GLOBAL_AS __attribute__((address_space(1)))
#define LDS_AS __attribute__((address_space(3)))

typedef unsigned short u16;
typedef unsigned int u32;
typedef __attribute__((ext_vector_type(4))) float f32x4;
typedef __attribute__((ext_vector_type(8))) short bf16x8;

// Model dims
#define TT 2048
#define EE 1024
#define NHH 16
#define HDD 64
#define HIDD 2816
#define VV 32000
#define MM 4096   // B*T

__device__ __forceinline__ u16 f2bf(float f) {
  u32 u = __builtin_bit_cast(u32, f);
  u += 0x7fffu + ((u >> 16) & 1u);
  return (u16)(u >> 16);
}
__device__ __forceinline__ float bf2f(u16 v) {
  return __builtin_bit_cast(float, (u32)v << 16);
}

// ---------------- elementwise / staging kernels ----------------

__global__ __launch_bounds__(256) void castbf_k(const float* __restrict__ in,
                                                u16* __restrict__ o, long n4) {
  const long i = (long)blockIdx.x * 256 + threadIdx.x;
  if (i >= n4) return;
  const float4 v = ((const float4*)in)[i];
  ((uint2*)o)[i] = make_uint2((u32)f2bf(v.x) | ((u32)f2bf(v.y) << 16),
                              (u32)f2bf(v.z) | ((u32)f2bf(v.w) << 16));
}

__global__ void ropetab_k(float* __restrict__ cosT, float* __restrict__ sinT) {
  const int t = blockIdx.x, j = threadIdx.x;  // j in [0,32)
  const float inv = powf(10000.0f, -(float)j * (1.0f / 32.0f));
  const float f = (float)t * inv;
  cosT[t * 32 + j] = cosf(f);
  sinT[t * 32 + j] = sinf(f);
}

__global__ __launch_bounds__(256) void embed_k(const int* __restrict__ idx,
                                               const float* __restrict__ temb,
                                               float* __restrict__ x) {
  const int row = blockIdx.x;
  const int id = idx[row];
  ((float4*)(x + (size_t)row * EE))[threadIdx.x] =
      ((const float4*)(temb + (size_t)id * EE))[threadIdx.x];
}

__global__ __launch_bounds__(256) void rmsnorm_k(const float* __restrict__ x,
                                                 const float* __restrict__ w,
                                                 u16* __restrict__ o) {
  __shared__ float red[4];
  const int row = blockIdx.x, tid = threadIdx.x;
  const float4 v = ((const float4*)(x + (size_t)row * EE))[tid];
  float ss = v.x * v.x + v.y * v.y + v.z * v.z + v.w * v.w;
#pragma unroll
  for (int off = 32; off; off >>= 1) ss += __shfl_xor(ss, off, 64);
  if ((tid & 63) == 0) red[tid >> 6] = ss;
  __syncthreads();
  const float inv = rsqrtf((red[0] + red[1] + red[2] + red[3]) * (1.0f / 1024.0f) + 1e-6f);
  const float4 wv = ((const float4*)w)[tid];
  const u32 lo = (u32)f2bf(v.x * inv * wv.x) | ((u32)f2bf(v.y * inv * wv.y) << 16);
  const u32 hi = (u32)f2bf(v.z * inv * wv.z) | ((u32)f2bf(v.w * inv * wv.w) << 16);
  ((uint2*)(o + (size_t)row * EE))[tid] = make_uint2(lo, hi);
}

// ---------------- GEMM engine: 256x256, BK=64, 4-phase counted-vmcnt dbuf (R5 engine) ----------------
// Used for the logits GEMM only (grid 2000 blocks). Best measured schedule (38% MfmaUtil).
template <int OUTBF>
__global__ __launch_bounds__(512, 2) void gemm256p(const u16* __restrict__ A,
                                                   const u16* __restrict__ Bw,
                                                   float* __restrict__ C,
                                                   u16* __restrict__ C16,
                                                   const u16* __restrict__ G,
                                                   int N, int K) {
  __shared__ u16 lds[2 * 32768];  // 128 KB
  const int t = threadIdx.x;
  const int lane = t & 63;
  const int wid = t >> 6;
  const int wr = wid >> 2;   // 0..1
  const int wc = wid & 3;    // 0..3
  const int l15 = lane & 15, lg = lane >> 4;
  const int bid = blockIdx.x;
  const int row0 = (bid & 15) << 8;
  const int col0 = (bid >> 4) << 8;
  const int NT = K >> 6;

  const int sr = t >> 3;
  const int su8 = (((t & 7) ^ (sr & 7)) << 3);  // pre-swizzled global elem offset
  const int t8 = t << 3;
  const u16* aG[4];
#pragma unroll
  for (int ga = 0; ga < 4; ++ga)
    aG[ga] = A + (size_t)(row0 + ga * 64 + sr) * K + su8;
  const u16* bG[4];
#pragma unroll
  for (int gb = 0; gb < 4; ++gb) {
    const int q = (gb * 2 + (sr >> 5)) & 3;
    const int nh = gb >> 1;
    bG[gb] = Bw + (size_t)(col0 + q * 64 + nh * 32 + (sr & 31)) * K + su8;
  }

  const int u0 = ((lg ^ (l15 & 7)) << 3);          // ks=0 unit
  const int u1 = (((4 | lg) ^ (l15 & 7)) << 3);    // ks=1 unit
  const int arow = (wr * 128 + l15) << 6;          // + m*1024
  const int brow = 16384 + ((wc * 32 + l15) << 6); // + nh*8192 + ni*1024

  f32x4 acc[8][4] = {};

#define STA(nb, ga, k0n)                                                              \
  __builtin_amdgcn_global_load_lds((const GLOBAL_AS void*)(aG[ga] + (k0n)),           \
                                   (LDS_AS void*)((nb) + (ga)*4096 + t8), 16, 0, 0)
#define STB(nb, gb, k0n)                                                              \
  __builtin_amdgcn_global_load_lds((const GLOBAL_AS void*)(bG[gb] + (k0n)),           \
                                   (LDS_AS void*)((nb) + 16384 + (gb)*4096 + t8), 16, 0, 0)

  {
    u16* nb = lds;
    STA(nb, 0, 0); STA(nb, 2, 0);
    STB(nb, 0, 0); STB(nb, 1, 0);
    STB(nb, 2, 0); STB(nb, 3, 0);
    STA(nb, 1, 0); STA(nb, 3, 0);
  }

  bf16x8 af[4][2], bl[2][2], bh[2][2];

  for (int kt = 0; kt < NT; ++kt) {
    const bool st = (kt + 1 < NT);
    const int k0n = (kt + 1) << 6;
    const u16* cb = lds + (kt & 1) * 32768;
    u16* nb = lds + ((kt + 1) & 1) * 32768;

    // ---- phase 0: mh=0, nh=0 ----
    asm volatile("s_waitcnt vmcnt(4)" ::: "memory");
    __builtin_amdgcn_s_barrier();
#pragma unroll
    for (int mi = 0; mi < 4; ++mi) {
      af[mi][0] = *(const bf16x8*)&cb[arow + mi * 1024 + u0];
      af[mi][1] = *(const bf16x8*)&cb[arow + mi * 1024 + u1];
    }
#pragma unroll
    for (int ni = 0; ni < 2; ++ni) {
      bl[ni][0] = *(const bf16x8*)&cb[brow + ni * 1024 + u0];
      bl[ni][1] = *(const bf16x8*)&cb[brow + ni * 1024 + u1];
    }
    if (st) { STA(nb, 0, k0n); STA(nb, 2, k0n); }
    __builtin_amdgcn_s_setprio(1);
#pragma unroll
    for (int mi = 0; mi < 4; ++mi)
#pragma unroll
      for (int ni = 0; ni < 2; ++ni) {
        acc[mi][ni] = __builtin_amdgcn_mfma_f32_16x16x32_bf16(af[mi][0], bl[ni][0], acc[mi][ni], 0, 0, 0);
        acc[mi][ni] = __builtin_amdgcn_mfma_f32_16x16x32_bf16(af[mi][1], bl[ni][1], acc[mi][ni], 0, 0, 0);
      }
    __builtin_amdgcn_s_setprio(0);

    // ---- phase 1: mh=0, nh=1 ----
    if (st) { asm volatile("s_waitcnt vmcnt(4)" ::: "memory"); }
    else    { asm volatile("s_waitcnt vmcnt(2)" ::: "memory"); }
    __builtin_amdgcn_s_barrier();
#pragma unroll
    for (int ni = 0; ni < 2; ++ni) {
      bh[ni][0] = *(const bf16x8*)&cb[brow + 8192 + ni * 1024 + u0];
      bh[ni][1] = *(const bf16x8*)&cb[brow + 8192 + ni * 1024 + u1];
    }
    if (st) { STB(nb, 0, k0n); STB(nb, 1, k0n); }
    __builtin_amdgcn_s_setprio(1);
#pragma unroll
    for (int mi = 0; mi < 4; ++mi)
#pragma unroll
      for (int ni = 0; ni < 2; ++ni) {
        acc[mi][2 + ni] = __builtin_amdgcn_mfma_f32_16x16x32_bf16(af[mi][0], bh[ni][0], acc[mi][2 + ni], 0, 0, 0);
        acc[mi][2 + ni] = __builtin_amdgcn_mfma_f32_16x16x32_bf16(af[mi][1], bh[ni][1], acc[mi][2 + ni], 0, 0, 0);
      }
    __builtin_amdgcn_s_setprio(0);

    // ---- phase 2: mh=1, nh=1 ----
    if (st) { asm volatile("s_waitcnt vmcnt(4)" ::: "memory"); }
    else    { asm volatile("s_waitcnt vmcnt(0)" ::: "memory"); }
    __builtin_amdgcn_s_barrier();
#pragma unroll
    for (int mi = 0; mi < 4; ++mi) {
      af[mi][0] = *(const bf16x8*)&cb[arow + (4 + mi) * 1024 + u0];
      af[mi][1] = *(const bf16x8*)&cb[arow + (4 + mi) * 1024 + u1];
    }
    if (st) { STB(nb, 2, k0n); STB(nb, 3, k0n); }
    __builtin_amdgcn_s_setprio(1);
#pragma unroll
    for (int mi = 0; mi < 4; ++mi)
#pragma unroll
      for (int ni = 0; ni < 2; ++ni) {
        acc[4 + mi][2 + ni] = __builtin_amdgcn_mfma_f32_16x16x32_bf16(af[mi][0], bh[ni][0], acc[4 + mi][2 + ni], 0, 0, 0);
        acc[4 + mi][2 + ni] = __builtin_amdgcn_mfma_f32_16x16x32_bf16(af[mi][1], bh[ni][1], acc[4 + mi][2 + ni], 0, 0, 0);
      }
    __builtin_amdgcn_s_setprio(0);

    // ---- phase 3: mh=1, nh=0 (no new reads) ----
    if (st) { STA(nb, 1, k0n); STA(nb, 3, k0n); }
    __builtin_amdgcn_s_setprio(1);
#pragma unroll
    for (int mi = 0; mi < 4; ++mi)
#pragma unroll
      for (int ni = 0; ni < 2; ++ni) {
        acc[4 + mi][ni] = __builtin_amdgcn_mfma_f32_16x16x32_bf16(af[mi][0], bl[ni][0], acc[4 + mi][ni], 0, 0, 0);
        acc[4 + mi][ni] = __builtin_amdgcn_mfma_f32_16x16x32_bf16(af[mi][1], bl[ni][1], acc[4 + mi][ni], 0, 0, 0);
      }
    __builtin_amdgcn_s_setprio(0);
  }
#undef STA
#undef STB

#pragma unroll
  for (int m = 0; m < 8; ++m) {
    const int row = row0 + wr * 128 + m * 16 + lg * 4;
#pragma unroll
    for (int n = 0; n < 4; ++n) {
      const int col = col0 + wc * 64 + n * 16 + l15;
#pragma unroll
      for (int r = 0; r < 4; ++r) {
        const size_t o = (size_t)(row + r) * N + col;
        if (OUTBF == 0) {
          C[o] = acc[m][n][r];
        } else if (OUTBF == 1) {
          C16[o] = f2bf(acc[m][n][r]);
        } else {
          const float g = bf2f(G[o]);
          C16[o] = f2bf(g / (1.0f + __expf(-g)) * acc[m][n][r]);
        }
      }
    }
  }
}

// ---------------- GEMM engine: 128x128, 8 waves (wave-tile 32x64), ring, epilogues ----------------
// Proven R8 ring schedule: 4-buf LDS ring, depth-3 prefetch, counted vmcnt 4/2/0.
// OUTBF: 0 f32 C = acc + R ; 3 rope-split (Q pre-scaled by 0.125*log2e for exp2 softmax).
template <int OUTBF>
__global__ __launch_bounds__(512, 2) void gemm128n(const u16* __restrict__ A,
                                                   const u16* __restrict__ Bw,
                                                   float* __restrict__ C,
                                                   const float* __restrict__ R,
                                                   const float* __restrict__ cosT,
                                                   const float* __restrict__ sinT,
                                                   u16* __restrict__ Qb,
                                                   u16* __restrict__ Kb,
                                                   u16* __restrict__ Vtb,
                                                   int N, int K) {
  __shared__ u16 lds[4 * 8192];  // 64 KB: 4 buffers x (A 128x32 | B 128x32)
  const int t = threadIdx.x;
  const int lane = t & 63;
  const int wid = t >> 6;
  const int wr = wid & 3;    // 0..3 : 32-row group
  const int wc = wid >> 2;   // 0..1 : 64-col group
  const int l15 = lane & 15, lg = lane >> 4;
  const int bid = blockIdx.x;
  const int row0 = (bid & 31) << 7;
  const int col0 = (bid >> 5) << 7;
  const int NT = K >> 5;

  const int rA = t >> 2;  // 0..127
  const int usw = (((t & 3) ^ ((t >> 3) & 3)) << 3);
  const u16* sA = A + (size_t)(row0 + rA) * K + usw;
  const u16* sB = Bw + (size_t)(col0 + rA) * K + usw;
  const int dst = t << 3;  // 0..4095

  const int e8 = ((lg ^ ((l15 >> 1) & 3)) << 3);
  const int aoff = (wr * 32 + l15) * 32 + e8;
  const int boff = 4096 + (wc * 64 + l15) * 32 + e8;

  f32x4 acc[2][4] = {};

  auto stage = [&](int kt) {
    u16* base = &lds[(kt & 3) * 8192];
    const size_t ko = (size_t)kt * 32;
    __builtin_amdgcn_global_load_lds((const GLOBAL_AS void*)(sA + ko),
                                     (LDS_AS void*)(base + dst), 16, 0, 0);
    __builtin_amdgcn_global_load_lds((const GLOBAL_AS void*)(sB + ko),
                                     (LDS_AS void*)(base + 4096 + dst), 16, 0, 0);
  };

  stage(0);
  stage(1);
  stage(2);

  for (int kt = 0; kt < NT; ++kt) {
    const int rem = NT - 1 - kt;
    if (rem >= 2) {
      asm volatile("s_waitcnt vmcnt(4)" ::: "memory");
    } else if (rem == 1) {
      asm volatile("s_waitcnt vmcnt(2)" ::: "memory");
    } else {
      asm volatile("s_waitcnt vmcnt(0)" ::: "memory");
    }
    __builtin_amdgcn_s_barrier();
    if (kt + 3 < NT) stage(kt + 3);
    const u16* base = &lds[(kt & 3) * 8192];
    bf16x8 af[2], bfv[4];
#pragma unroll
    for (int m = 0; m < 2; ++m) af[m] = *(const bf16x8*)&base[aoff + m * 512];
#pragma unroll
    for (int n = 0; n < 4; ++n) bfv[n] = *(const bf16x8*)&base[boff + n * 512];
    __builtin_amdgcn_s_setprio(1);
#pragma unroll
    for (int m = 0; m < 2; ++m)
#pragma unroll
      for (int n = 0; n < 4; ++n)
        acc[m][n] = __builtin_amdgcn_mfma_f32_16x16x32_bf16(af[m], bfv[n], acc[m][n], 0, 0, 0);
    __builtin_amdgcn_s_setprio(0);
  }

  if (OUTBF == 3) {
    // fused RoPE + QKV split. Tile entirely in Q (col0<1024), K, or V region.
    const int reg = col0 >> 10;
    const int fb = col0 & 1023;
#pragma unroll
    for (int m = 0; m < 2; ++m) {
      const int row = row0 + wr * 32 + m * 16 + lg * 4;
      const int b = row >> 11, tbase = row & 2047;
      if (reg < 2) {
        u16* dstp = (reg == 0) ? Qb : Kb;
        // Q pre-scaled by 0.125*log2(e) so attn softmax uses raw v_exp_f32 (2^x).
        const float qs = (reg == 0) ? 0.18033688011112042f : 1.0f;
#pragma unroll
        for (int n = 0; n < 2; ++n) {
          const int f = fb + wc * 64 + n * 16 + l15;
          const int h = f >> 6, j = f & 63;  // j < 32
#pragma unroll
          for (int r = 0; r < 4; ++r) {
            const int tt = tbase + r;
            const float c = cosT[tt * 32 + j], s = sinT[tt * 32 + j];
            const float x1 = acc[m][n][r], x2 = acc[m][n | 2][r];
            const size_t ro = ((size_t)(b * NHH + h) * TT + tt) * HDD + j;
            dstp[ro] = f2bf((x1 * c - x2 * s) * qs);
            dstp[ro + 32] = f2bf((x1 * s + x2 * c) * qs);
          }
        }
      } else {
#pragma unroll
        for (int n = 0; n < 4; ++n) {
          const int f = fb + wc * 64 + n * 16 + l15;
          const int h = f >> 6, j = f & 63;
          ushort4 pk;
          pk.x = f2bf(acc[m][n][0]);
          pk.y = f2bf(acc[m][n][1]);
          pk.z = f2bf(acc[m][n][2]);
          pk.w = f2bf(acc[m][n][3]);
          *(ushort4*)&Vtb[((size_t)(b * NHH + h) * HDD + j) * TT + tbase] = pk;
        }
      }
    }
    return;
  }

#pragma unroll
  for (int m = 0; m < 2; ++m) {
    const int row = row0 + wr * 32 + m * 16 + lg * 4;
#pragma unroll
    for (int n = 0; n < 4; ++n) {
      const int col = col0 + wc * 64 + n * 16 + l15;
#pragma unroll
      for (int r = 0; r < 4; ++r) {
        const size_t o = (size_t)(row + r) * N + col;
        C[o] = acc[m][n][r] + R[o];
      }
    }
  }
}

// ---------------- GEMM engine: dual-B 128x64, computes g=A*W1^T and u=A*W2^T, ----------------
// writes silu(g)*u in one pass. Ring: 3 bufs x 16KB, depth-2, counted vmcnt 2/0.
// Staging: A by all 8 waves (8KB); Bg by waves 0-3, Bu by waves 4-7 (4KB each)
// -> every wave issues exactly 2 glds/stage, so per-wave vmcnt math is uniform.
// 8 waves as 4(m: 32 rows) x 2(n: 32 cols); per-wave acc_g[2][2] + acc_u[2][2].
__global__ __launch_bounds__(512, 2) void gemm128d(const u16* __restrict__ A,
                                                   const u16* __restrict__ Bg,
                                                   const u16* __restrict__ Bu,
                                                   u16* __restrict__ C16,
                                                   int N, int K) {
  __shared__ u16 lds[3 * 8192];  // 48 KB: 3 bufs x (A 4096 | Bg 2048 | Bu 2048) u16
  const int t = threadIdx.x;
  const int lane = t & 63;
  const int wid = t >> 6;
  const int wr = wid & 3;    // 32-row group
  const int wc = wid >> 2;   // 0..1 : 32-col group
  const int l15 = lane & 15, lg = lane >> 4;
  const int bid = blockIdx.x;
  const int row0 = (bid & 31) << 7;   // 32 row tiles of 128
  const int col0 = (bid >> 5) << 6;   // 64-col tiles
  const int NT = K >> 5;

  const int rA = t >> 2;              // 0..127
  const int usw = (((t & 3) ^ ((t >> 3) & 3)) << 3);
  const u16* sA = A + (size_t)(row0 + rA) * K + usw;
  const int tb = t & 255;
  const int rB = tb >> 2;             // 0..63
  const int uswB = (((tb & 3) ^ ((tb >> 3) & 3)) << 3);
  const u16* sB = ((wid < 4) ? Bg : Bu) + (size_t)(col0 + rB) * K + uswB;
  const int dstA = t << 3;
  const int dstB = 4096 + ((wid < 4) ? 0 : 2048) + (tb << 3);

  const int e8 = ((lg ^ ((l15 >> 1) & 3)) << 3);
  const int aoff = (wr * 32 + l15) * 32 + e8;
  const int goff = 4096 + (wc * 32 + l15) * 32 + e8;
  const int uoff = 6144 + (wc * 32 + l15) * 32 + e8;

  f32x4 ag[2][2] = {}, au[2][2] = {};

  auto stage = [&](int kt, int buf) {
    u16* b = &lds[buf * 8192];
    const size_t ko = (size_t)kt * 32;
    __builtin_amdgcn_global_load_lds((const GLOBAL_AS void*)(sA + ko),
                                     (LDS_AS void*)(b + dstA), 16, 0, 0);
    __builtin_amdgcn_global_load_lds((const GLOBAL_AS void*)(sB + ko),
                                     (LDS_AS void*)(b + dstB), 16, 0, 0);
  };

  stage(0, 0);
  stage(1, 1);

  int cbuf = 0;
  for (int kt = 0; kt < NT; ++kt) {
    if (kt + 1 < NT) {
      asm volatile("s_waitcnt vmcnt(2)" ::: "memory");
    } else {
      asm volatile("s_waitcnt vmcnt(0)" ::: "memory");
    }
    __builtin_amdgcn_s_barrier();
    const int nbuf = (cbuf == 2) ? 0 : cbuf + 1;
    const int sbuf = (nbuf == 2) ? 0 : nbuf + 1;
    if (kt + 2 < NT) stage(kt + 2, sbuf);
    const u16* cb = &lds[cbuf * 8192];
    bf16x8 af[2], bgv[2], buv[2];
#pragma unroll
    for (int m = 0; m < 2; ++m) af[m] = *(const bf16x8*)&cb[aoff + m * 512];
#pragma unroll
    for (int n = 0; n < 2; ++n) {
      bgv[n] = *(const bf16x8*)&cb[goff + n * 512];
      buv[n] = *(const bf16x8*)&cb[uoff + n * 512];
    }
    __builtin_amdgcn_s_setprio(1);
#pragma unroll
    for (int m = 0; m < 2; ++m)
#pragma unroll
      for (int n = 0; n < 2; ++n) {
        ag[m][n] = __builtin_amdgcn_mfma_f32_16x16x32_bf16(af[m], bgv[n], ag[m][n], 0, 0, 0);
        au[m][n] = __builtin_amdgcn_mfma_f32_16x16x32_bf16(af[m], buv[n], au[m][n], 0, 0, 0);
      }
    __builtin_amdgcn_s_setprio(0);
    cbuf = nbuf;
  }

#pragma unroll
  for (int m = 0; m < 2; ++m) {
    const int row = row0 + wr * 32 + m * 16 + lg * 4;
#pragma unroll
    for (int n = 0; n < 2; ++n) {
      const int col = col0 + wc * 32 + n * 16 + l15;
#pragma unroll
      for (int r = 0; r < 4; ++r) {
        const float g = ag[m][n][r];
        const float u = au[m][n][r];
        C16[(size_t)(row + r) * N + col] = f2bf(g / (1.0f + __expf(-g)) * u);
      }
    }
  }
}

// ---------------- attention: flash-style, no-max exp2 softmax (Q pre-scaled), ----------------
// denominator via MFMA row-sum; P->bf16 via v_cvt_pk; causal load-balanced grid.
__global__ __launch_bounds__(256) void attn_k(const u16* __restrict__ Q,
                                              const u16* __restrict__ Kc,
                                              const u16* __restrict__ Vt,
                                              u16* __restrict__ O) {
  __shared__ u16 P_lds[4][32][72];
  const int bid = blockIdx.x;           // 512 blocks
  const int bh = bid & 31;
  const int jj = bid >> 5;              // 0..15
  const int qi = (bid < 256) ? jj : 23 - jj;
  const int q0 = qi << 7;
  const int lane = threadIdx.x & 63;
  const int w = threadIdx.x >> 6;
  const int l15 = lane & 15, lg = lane >> 4;
  const int qbase = q0 + w * 32;

  bf16x8 qf[2][2];
#pragma unroll
  for (int am = 0; am < 2; ++am)
#pragma unroll
    for (int ks = 0; ks < 2; ++ks)
      qf[am][ks] = *(const bf16x8*)&Q[((size_t)bh * TT + qbase + am * 16 + l15) * HDD + ks * 32 + lg * 8];

  bf16x8 ones;
#pragma unroll
  for (int i = 0; i < 8; ++i) ones[i] = (short)0x3F80;  // bf16 1.0

  f32x4 oacc[2][4] = {};
  f32x4 lacc[2] = {};

  const int ntile = (q0 + 128) >> 6;
  for (int kt = 0; kt < ntile; ++kt) {
    const int k0 = kt << 6;
    f32x4 s[2][4];
    bf16x8 kf0[4], kf1[4];
#pragma unroll
    for (int an = 0; an < 4; ++an) {
      kf0[an] = *(const bf16x8*)&Kc[((size_t)bh * TT + k0 + an * 16 + l15) * HDD + lg * 8];
      kf1[an] = *(const bf16x8*)&Kc[((size_t)bh * TT + k0 + an * 16 + l15) * HDD + 32 + lg * 8];
    }
    __builtin_amdgcn_s_setprio(1);
#pragma unroll
    for (int an = 0; an < 4; ++an) {
#pragma unroll
      for (int am = 0; am < 2; ++am) {
        f32x4 z = {0.0f, 0.0f, 0.0f, 0.0f};
        z = __builtin_amdgcn_mfma_f32_16x16x32_bf16(qf[am][0], kf0[an], z, 0, 0, 0);
        s[am][an] = __builtin_amdgcn_mfma_f32_16x16x32_bf16(qf[am][1], kf1[an], z, 0, 0, 0);
      }
    }
    __builtin_amdgcn_s_setprio(0);
    // causal mask + 2^x (Q pre-scaled by 0.125*log2e; scores bounded, f32-safe)
    const bool diag = (k0 + 64) > q0;
#pragma unroll
    for (int am = 0; am < 2; ++am)
#pragma unroll
      for (int an = 0; an < 4; ++an)
#pragma unroll
        for (int r = 0; r < 4; ++r) {
          float v = s[am][an][r];
          if (diag) {
            const int qrow = qbase + am * 16 + lg * 4 + r;
            const int kcol = k0 + an * 16 + l15;
            if (kcol > qrow) v = -1e30f;
          }
          float p;
          asm("v_exp_f32 %0, %1" : "=v"(p) : "v"(v));
          s[am][an][r] = p;
        }
    // P -> LDS via packed bf16 conversion, then PV + l-sum MFMA
#pragma unroll
    for (int am = 0; am < 2; ++am)
#pragma unroll
      for (int an = 0; an < 4; ++an)
#pragma unroll
        for (int rp = 0; rp < 2; ++rp) {
          u32 pk;
          asm("v_cvt_pk_bf16_f32 %0, %1, %2"
              : "=v"(pk) : "v"(s[am][an][2 * rp]), "v"(s[am][an][2 * rp + 1]));
          const int rowb = am * 16 + lg * 4 + 2 * rp;
          P_lds[w][rowb][an * 16 + l15] = (u16)pk;
          P_lds[w][rowb + 1][an * 16 + l15] = (u16)(pk >> 16);
        }
#pragma unroll
    for (int ks = 0; ks < 2; ++ks) {
      bf16x8 pf[2];
#pragma unroll
      for (int am = 0; am < 2; ++am)
        pf[am] = *(const bf16x8*)&P_lds[w][am * 16 + l15][ks * 32 + lg * 8];
      __builtin_amdgcn_s_setprio(1);
#pragma unroll
      for (int dn = 0; dn < 4; ++dn) {
        const bf16x8 vf = *(const bf16x8*)&Vt[((size_t)bh * HDD + dn * 16 + l15) * TT + k0 + ks * 32 + lg * 8];
#pragma unroll
        for (int am = 0; am < 2; ++am)
          oacc[am][dn] = __builtin_amdgcn_mfma_f32_16x16x32_bf16(pf[am], vf, oacc[am][dn], 0, 0, 0);
      }
#pragma unroll
      for (int am = 0; am < 2; ++am)
        lacc[am] = __builtin_amdgcn_mfma_f32_16x16x32_bf16(pf[am], ones, lacc[am], 0, 0, 0);
      __builtin_amdgcn_s_setprio(0);
    }
  }
  const int b = bh >> 4, h = bh & 15;
#pragma unroll
  for (int am = 0; am < 2; ++am)
#pragma unroll
    for (int r = 0; r < 4; ++r) {
      const float il = 1.0f / lacc[am][r];
      const int qrow = qbase + am * 16 + lg * 4 + r;
#pragma unroll
      for (int dn = 0; dn < 4; ++dn)
        O[((size_t)b * TT + qrow) * EE + h * 64 + dn * 16 + l15] = f2bf(oacc[am][dn][r] * il);
    }
}

// ---------------- host ----------------

extern "C" void kernel_launch(void* const* d_in, const int* in_sizes, int n_in,
                              void* d_out, int out_size, void* d_ws, size_t ws_size,
                              hipStream_t stream) {
  const int* idx = (const int*)d_in[0];
  const float* tok_emb = (const float*)d_in[1];
  const float* qkv_w = (const float*)d_in[2];
  const float* proj_w = (const float*)d_in[3];
  const float* w1 = (const float*)d_in[4];
  const float* w2 = (const float*)d_in[5];
  const float* w3 = (const float*)d_in[6];
  const float* norm1_w = (const float*)d_in[7];
  const float* norm2_w = (const float*)d_in[8];
  const float* norm_f_w = (const float*)d_in[9];
  float* out = (float*)d_out;

  char* ws = (char*)d_ws;
  size_t off = 0;
  auto alloc = [&](size_t bytes) -> void* {
    off = (off + 255) & ~(size_t)255;
    void* p = ws + off;
    off += bytes;
    return p;
  };

  const size_t N_TEMB = (size_t)VV * EE;
  const size_t N_QKVW = (size_t)8 * 3 * EE * EE;
  const size_t N_PROJW = (size_t)8 * EE * EE;
  const size_t N_W1 = (size_t)8 * HIDD * EE;
  const size_t N_W3 = (size_t)8 * EE * HIDD;

  u16* tembbf = (u16*)alloc(N_TEMB * 2);
  u16* qkvwbf = (u16*)alloc(N_QKVW * 2);
  u16* projwbf = (u16*)alloc(N_PROJW * 2);
  u16* w1bf = (u16*)alloc(N_W1 * 2);
  u16* w2bf = (u16*)alloc(N_W1 * 2);
  u16* w3bf = (u16*)alloc(N_W3 * 2);
  float* x = (float*)alloc((size_t)MM * EE * 4);
  u16* h1 = (u16*)alloc((size_t)MM * EE * 2);
  u16* hg = (u16*)alloc((size_t)MM * HIDD * 2);
  u16* qb = (u16*)alloc((size_t)2 * NHH * TT * HDD * 2);
  u16* kb = (u16*)alloc((size_t)2 * NHH * TT * HDD * 2);
  u16* vtb = (u16*)alloc((size_t)2 * NHH * TT * HDD * 2);
  u16* attno = (u16*)alloc((size_t)MM * EE * 2);
  float* cosT = (float*)alloc((size_t)TT * 32 * 4);
  float* sinT = (float*)alloc((size_t)TT * 32 * 4);

  auto cast = [&](const float* src, u16* dst, size_t n) {
    const long n4 = (long)(n / 4);
    castbf_k<<<(int)((n4 + 255) / 256), 256, 0, stream>>>(src, dst, n4);
  };
  cast(tok_emb, tembbf, N_TEMB);
  cast(qkv_w, qkvwbf, N_QKVW);
  cast(proj_w, projwbf, N_PROJW);
  cast(w1, w1bf, N_W1);
  cast(w2, w2bf, N_W1);
  cast(w3, w3bf, N_W3);

  ropetab_k<<<TT, 32, 0, stream>>>(cosT, sinT);
  embed_k<<<MM, 256, 0, stream>>>(idx, tok_emb, x);

  for (int l = 0; l < 8; ++l) {
    rmsnorm_k<<<MM, 256, 0, stream>>>(x, norm1_w + l * EE, h1);
    gemm128n<3><<<dim3(24 * 32), 512, 0, stream>>>(h1, qkvwbf + (size_t)l * 3 * EE * EE,
                                                   nullptr, nullptr,
                                                   cosT, sinT, qb, kb, vtb, 3 * EE, EE);
    attn_k<<<dim3(512), 256, 0, stream>>>(qb, kb, vtb, attno);
    gemm128n<0><<<dim3(8 * 32), 512, 0, stream>>>(attno, projwbf + (size_t)l * EE * EE,
                                                  x, x,
                                                  nullptr, nullptr, nullptr, nullptr, nullptr,
                                                  EE, EE);
    rmsnorm_k<<<MM, 256, 0, stream>>>(x, norm2_w + l * EE, h1);
    gemm128d<<<dim3(44 * 32), 512, 0, stream>>>(h1, w1bf + (size_t)l * HIDD * EE,
                                                w2bf + (size_t)l * HIDD * EE,
                                                hg, HIDD, EE);
    gemm128n<0><<<dim3(8 * 32), 512, 0, stream>>>(hg, w3bf + (size_t)l * EE * HIDD,
                                                  x, x,
                                                  nullptr, nullptr, nullptr, nullptr, nullptr,
                                                  EE, HIDD);
  }
  rmsnorm_k<<<MM, 256, 0, stream>>>(x, norm_f_w, h1);
  gemm256p<0><<<dim3(125 * 16), 512, 0, stream>>>(h1, tembbf, out, nullptr, nullptr,
                                                  VV, EE);
}